// Round 1
// baseline (2791.070 us; speedup 1.0000x reference)
//
#include <hip/hip_runtime.h>
#include <cmath>

// ---------------------------------------------------------------------------
// InvariantSlotAttention forward, f32 baseline.
// B=16, S=7, E=HID=64, D=4096, N_ITER=3, TSOFT=0.125
// grid[d] = (-0.5 + (d%64)/63, -0.5 + (d/64)/63)
// ---------------------------------------------------------------------------

#define RLOW_F 0.1f
#define RHIGH_F 0.22360679774997896f

__device__ __forceinline__ float wsum64(float v){
  #pragma unroll
  for (int off = 32; off > 0; off >>= 1) v += __shfl_xor(v, off, 64);
  return v;
}
__device__ __forceinline__ float rdlane(float v, int l){
  return __int_as_float(__builtin_amdgcn_readlane(__float_as_int(v), l));
}

// ---------------- init: queries = mu + exp(logsig)*noise ; pos_scale -------
__global__ void k_prep(const float* __restrict__ noise, const float* __restrict__ prand,
                       const float* __restrict__ mu, const float* __restrict__ logsig,
                       float* __restrict__ queries, float* __restrict__ ps){
  int row = blockIdx.x;            // b*7+s, 112 blocks
  int e = threadIdx.x;             // 64
  int s = row % 7;
  queries[row*64 + e] = mu[e] + expf(logsig[e]) * noise[row*64 + e];
  if (e < 3){
    float pr = prand[row*3 + e];
    float v;
    if (s < 2)      v = pr - 0.5f;                      // source indexes slot dim
    else if (s == 6) v = (RLOW_F - RHIGH_F)*pr + RHIGH_F;
    else            v = pr;
    ps[row*3 + e] = v;
  }
}

// ---------------- conv0: 1->64 channels, 5x5 same, relu ---------------------
__global__ __launch_bounds__(256) void k_conv0(const float* __restrict__ in,
                        const float* __restrict__ w, const float* __restrict__ bias,
                        float* __restrict__ out){
  int bi = blockIdx.x; int b = bi >> 6; int y = bi & 63;   // 1024 blocks
  int t = threadIdx.x; int lane = t & 63; int xg = t >> 6;
  __shared__ float s_in[5*68];
  __shared__ float s_w[64*25];
  __shared__ float s_out[64*65];
  for (int i = t; i < 1600; i += 256) s_w[i] = w[i];
  for (int i = t; i < 340; i += 256){
    int r = i / 68, cx = i % 68;
    int yy = y + r - 2, gx = cx - 2;
    float v = 0.f;
    if (yy >= 0 && yy < 64 && gx >= 0 && gx < 64) v = in[(b*64 + yy)*64 + gx];
    s_in[r*68 + cx] = v;
  }
  __syncthreads();
  int o = lane;
  float bv = bias[o];
  float acc[16];
  #pragma unroll
  for (int k = 0; k < 16; k++) acc[k] = bv;
  #pragma unroll
  for (int ky = 0; ky < 5; ky++){
    float rv[20];
    const float4* p = reinterpret_cast<const float4*>(&s_in[ky*68 + xg*16]);
    #pragma unroll
    for (int q = 0; q < 5; q++){ float4 f = p[q]; rv[q*4]=f.x; rv[q*4+1]=f.y; rv[q*4+2]=f.z; rv[q*4+3]=f.w; }
    #pragma unroll
    for (int kx = 0; kx < 5; kx++){
      float wv = s_w[o*25 + ky*5 + kx];
      #pragma unroll
      for (int k = 0; k < 16; k++) acc[k] = fmaf(rv[k+kx], wv, acc[k]);
    }
  }
  #pragma unroll
  for (int k = 0; k < 16; k++) s_out[o*65 + xg*16 + k] = fmaxf(acc[k], 0.f);
  __syncthreads();
  #pragma unroll
  for (int k = 0; k < 16; k++){
    int oo = xg + 4*k;
    out[((b*64 + oo)*64 + y)*64 + lane] = s_out[oo*65 + lane];
  }
}

// ---------------- weight transpose [o][c][ky][kx] -> [c][ky][kx][o] --------
__global__ void k_wtrans(const float* __restrict__ w, float* __restrict__ wt){
  int idx = blockIdx.x*256 + threadIdx.x;
  if (idx >= 102400) return;
  int o = idx / 1600; int rem = idx % 1600;  // rem = c*25 + ky*5 + kx
  wt[rem*64 + o] = w[idx];
}

// ---------------- conv1/conv2: 64->64 channels, 5x5 same, relu -------------
__global__ __launch_bounds__(256) void k_conv(const float* __restrict__ in,
                       const float* __restrict__ wt, const float* __restrict__ bias,
                       float* __restrict__ out){
  int bi = blockIdx.x; int b = bi >> 6; int y = bi & 63;
  int t = threadIdx.x; int lane = t & 63; int xg = t >> 6;
  __shared__ float s_in[16*5*68];
  __shared__ float s_out[64*65];
  int o = lane;
  float bv = bias[o];
  float acc[16];
  #pragma unroll
  for (int k = 0; k < 16; k++) acc[k] = bv;
  for (int cc0 = 0; cc0 < 64; cc0 += 16){
    __syncthreads();
    for (int rid = xg; rid < 80; rid += 4){
      int c = rid / 5, r = rid % 5;
      int yy = y + r - 2;
      float v = 0.f;
      if (yy >= 0 && yy < 64) v = in[((b*64 + cc0 + c)*64 + yy)*64 + lane];
      s_in[(c*5+r)*68 + lane + 2] = v;
      if (lane < 2)   s_in[(c*5+r)*68 + lane] = 0.f;
      if (lane >= 62) s_in[(c*5+r)*68 + lane + 4] = 0.f;
    }
    __syncthreads();
    for (int c = 0; c < 16; c++){
      #pragma unroll
      for (int ky = 0; ky < 5; ky++){
        float rv[20];
        const float4* p = reinterpret_cast<const float4*>(&s_in[(c*5+ky)*68 + xg*16]);
        #pragma unroll
        for (int q = 0; q < 5; q++){ float4 f = p[q]; rv[q*4]=f.x; rv[q*4+1]=f.y; rv[q*4+2]=f.z; rv[q*4+3]=f.w; }
        const float* wp = &wt[((cc0+c)*25 + ky*5)*64 + o];
        float wv[5];
        #pragma unroll
        for (int kx = 0; kx < 5; kx++) wv[kx] = wp[kx*64];
        #pragma unroll
        for (int kx = 0; kx < 5; kx++){
          #pragma unroll
          for (int k = 0; k < 16; k++) acc[k] = fmaf(rv[k+kx], wv[kx], acc[k]);
        }
      }
    }
  }
  __syncthreads();
  #pragma unroll
  for (int k = 0; k < 16; k++) s_out[o*65 + xg*16 + k] = fmaxf(acc[k], 0.f);
  __syncthreads();
  #pragma unroll
  for (int k = 0; k < 16; k++){
    int oo = xg + 4*k;
    out[((b*64 + oo)*64 + y)*64 + lane] = s_out[oo*65 + lane];
  }
}

// ---------------- NCHW -> [b][d][c] + LayerNorm(dataN) ---------------------
__global__ __launch_bounds__(256) void k_encln(const float* __restrict__ in,
                        const float* __restrict__ g, const float* __restrict__ be,
                        float* __restrict__ enc){
  int bi = blockIdx.x; int b = bi >> 6; int y = bi & 63;
  int t = threadIdx.x; int lane = t & 63; int w = t >> 6;
  __shared__ float tile[64*65];
  for (int k = 0; k < 16; k++){
    int c = w + 4*k;
    tile[c*65 + lane] = in[((b*64 + c)*64 + y)*64 + lane];
  }
  __syncthreads();
  float gv = g[lane], bb = be[lane];
  for (int k = 0; k < 16; k++){
    int x = w*16 + k;
    float v = tile[lane*65 + x];            // lane = channel
    float m = wsum64(v) * (1.f/64.f);
    float d = v - m;
    float var = wsum64(d*d) * (1.f/64.f);
    float ov = d * (1.0f/sqrtf(var + 1e-5f)) * gv + bb;
    enc[(b*4096 + y*64 + x)*64 + lane] = ov;
  }
}

// ---------------- enc @ toK_w , enc @ toV_w --------------------------------
__global__ __launch_bounds__(256) void k_proj(const float* __restrict__ enc,
                       const float* __restrict__ wk, const float* __restrict__ bk,
                       const float* __restrict__ wv, const float* __restrict__ bvp,
                       float* __restrict__ K, float* __restrict__ V){
  int bi = blockIdx.x; int b = bi >> 6; int tile = bi & 63;  // 1024 blocks
  int t = threadIdx.x; int j = t & 63; int w = t >> 6;
  __shared__ float W1[4096];
  __shared__ float W2[4096];
  for (int i = t; i < 4096; i += 256){ W1[i] = wk[i]; W2[i] = wv[i]; }
  int d0 = tile*64 + w*16;
  float x[16];
  #pragma unroll
  for (int r = 0; r < 16; r++) x[r] = enc[(b*4096 + d0 + r)*64 + j];
  __syncthreads();
  float aK[16], aV[16];
  float bkv = bk[j], bvv = bvp[j];
  #pragma unroll
  for (int r = 0; r < 16; r++){ aK[r] = bkv; aV[r] = bvv; }
  for (int i = 0; i < 64; i++){
    float w1 = W1[i*64 + j], w2 = W2[i*64 + j];
    #pragma unroll
    for (int r = 0; r < 16; r++){
      float xv = rdlane(x[r], i);
      aK[r] = fmaf(xv, w1, aK[r]);
      aV[r] = fmaf(xv, w2, aV[r]);
    }
  }
  #pragma unroll
  for (int r = 0; r < 16; r++){
    K[(b*4096 + d0 + r)*64 + j] = aK[r];
    V[(b*4096 + d0 + r)*64 + j] = aV[r];
  }
}

// ---------------- per-phase prep: LN(queries), A/B/cc, zero accumulators ---
__global__ void k_phaseprep(const float* __restrict__ queries, const float* __restrict__ ps,
                            const float* __restrict__ qg_, const float* __restrict__ qb_,
                            const float* __restrict__ dw, const float* __restrict__ db,
                            float* __restrict__ qln, float* __restrict__ absc,
                            float* __restrict__ sum_att, float* __restrict__ upd){
  int row = blockIdx.x; int e = threadIdx.x;   // 112 x 64
  float q = queries[row*64 + e];
  float m = wsum64(q) * (1.f/64.f);
  float d = q - m;
  float var = wsum64(d*d) * (1.f/64.f);
  qln[row*64 + e] = d * (1.0f/sqrtf(var + 1e-5f)) * qg_[e] + qb_[e];
  float px = ps[row*3], py = ps[row*3+1], sc = ps[row*3+2];
  float A  = dw[e]      / sc;
  float Bv = dw[64 + e] / sc;
  absc[(row*3+0)*64 + e] = A;
  absc[(row*3+1)*64 + e] = Bv;
  absc[(row*3+2)*64 + e] = db[e] - px*A - py*Bv;
  upd[row*64 + e] = 0.f;
  if (e == 0) sum_att[row] = 0.f;
}

// ---------------- the heavy pass: per-(b,s,d) LN+MLP, then logit or upd ----
// mode 0: outp = logits buffer [B,S,D]; mode 1: outp = upd [B,S,E] (atomic)
__global__ __launch_bounds__(256) void k_kv(const float* __restrict__ encX,
     const float* __restrict__ mlp1w, const float* __restrict__ mlp1b,
     const float* __restrict__ mlp2w, const float* __restrict__ mlp2b,
     const float* __restrict__ qg_, const float* __restrict__ qb_,
     const float* __restrict__ absc, const float* __restrict__ qln,
     const float* __restrict__ att, const float* __restrict__ sum_att,
     float* __restrict__ outp, int mode){
  int bi = blockIdx.x;                 // 7168 = 112*64
  int tile = bi & 63; int bs = bi >> 6;
  int b = bs / 7;
  int t = threadIdx.x; int j = t & 63; int w = t >> 6;
  __shared__ float W1[4096];
  __shared__ float W2[4096];
  __shared__ float red[4*64];
  for (int i = t; i < 4096; i += 256){ W1[i] = mlp1w[i]; W2[i] = mlp2w[i]; }
  float A  = absc[(bs*3+0)*64 + j];
  float Bv = absc[(bs*3+1)*64 + j];
  float C  = absc[(bs*3+2)*64 + j];
  float qg = qg_[j], qb = qb_[j];
  float b1 = mlp1b[j], b2 = mlp2b[j];
  int d0 = tile*64 + w*16;
  float x[16];
  #pragma unroll
  for (int r = 0; r < 16; r++){
    int d = d0 + r;
    float gx = -0.5f + (float)(d & 63) * (1.f/63.f);
    float gy = -0.5f + (float)(d >> 6) * (1.f/63.f);
    x[r] = encX[(b*4096 + d)*64 + j] + gx*A + gy*Bv + C;
  }
  #pragma unroll
  for (int r = 0; r < 16; r++){
    float v = x[r];
    float m = wsum64(v) * (1.f/64.f);
    float dd = v - m;
    float var = wsum64(dd*dd) * (1.f/64.f);
    x[r] = dd * (1.0f/sqrtf(var + 1e-5f)) * qg + qb;
  }
  __syncthreads();
  float y[16];
  #pragma unroll
  for (int r = 0; r < 16; r++) y[r] = b1;
  for (int i = 0; i < 64; i++){
    float wv = W1[i*64 + j];
    #pragma unroll
    for (int r = 0; r < 16; r++) y[r] = fmaf(rdlane(x[r], i), wv, y[r]);
  }
  #pragma unroll
  for (int r = 0; r < 16; r++) y[r] = fmaxf(y[r], 0.f);
  float z[16];
  #pragma unroll
  for (int r = 0; r < 16; r++) z[r] = b2;
  for (int i = 0; i < 64; i++){
    float wv = W2[i*64 + j];
    #pragma unroll
    for (int r = 0; r < 16; r++) z[r] = fmaf(rdlane(y[r], i), wv, z[r]);
  }
  if (mode == 0){
    float qv = qln[bs*64 + j];
    #pragma unroll
    for (int r = 0; r < 16; r++){
      float lv = wsum64(z[r] * qv) * 0.125f;     // TSOFT = 1/sqrt(64)
      if (j == 0) outp[bs*4096 + d0 + r] = lv;
    }
  } else {
    float sa = sum_att[bs];
    float av = (j < 16) ? att[bs*4096 + d0 + j] : 0.f;
    float part = 0.f;
    #pragma unroll
    for (int r = 0; r < 16; r++){
      float wr = rdlane(av, r) / sa + 1e-8f;
      part = fmaf(wr, z[r], part);
    }
    red[w*64 + j] = part;
    __syncthreads();
    if (t < 64){
      float tot = red[t] + red[64+t] + red[128+t] + red[192+t];
      atomicAdd(&outp[bs*64 + t], tot);
    }
  }
}

// ---------------- softmax over slots (axis=1) + per-(b,s) sums -------------
__global__ void k_softmax(float* __restrict__ att, float* __restrict__ sum_att){
  int bi = blockIdx.x;                 // 256 = B * (D/256)
  int b = bi >> 4;
  int t = threadIdx.x;
  int d = (bi & 15)*256 + t;
  int lane = t & 63; int w = t >> 6;
  __shared__ float red[4];
  float l[7];
  #pragma unroll
  for (int s = 0; s < 7; s++) l[s] = att[(b*7+s)*4096 + d];
  float m = l[0];
  #pragma unroll
  for (int s = 1; s < 7; s++) m = fmaxf(m, l[s]);
  float sum = 0.f;
  #pragma unroll
  for (int s = 0; s < 7; s++){ l[s] = expf(l[s] - m); sum += l[s]; }
  for (int s = 0; s < 7; s++){
    float a = l[s] / sum;
    att[(b*7+s)*4096 + d] = a;
    float ws = wsum64(a);
    if (lane == 0) red[w] = ws;
    __syncthreads();
    if (t == 0) atomicAdd(&sum_att[b*7+s], red[0]+red[1]+red[2]+red[3]);
    __syncthreads();
  }
}

// ---------------- update_frames: pos = wts@grid, scale via exact identity --
__global__ void k_frames(const float* __restrict__ att, const float* __restrict__ sum_att,
                         float* __restrict__ psout){
  int bs = blockIdx.x; int t = threadIdx.x;   // 112 x 256
  float sa = sum_att[bs];
  float a0 = 0.f, ax = 0.f, ay = 0.f, a2 = 0.f;
  for (int d = t; d < 4096; d += 256){
    float wv = att[bs*4096 + d] / sa + 1e-8f;
    float gx = -0.5f + (float)(d & 63) * (1.f/63.f);
    float gy = -0.5f + (float)(d >> 6) * (1.f/63.f);
    a0 += wv; ax += wv*gx; ay += wv*gy; a2 += wv*(gx*gx + gy*gy);
  }
  __shared__ float red[4][4];
  int lane = t & 63, w = t >> 6;
  a0 = wsum64(a0); ax = wsum64(ax); ay = wsum64(ay); a2 = wsum64(a2);
  if (lane == 0){ red[w][0]=a0; red[w][1]=ax; red[w][2]=ay; red[w][3]=a2; }
  __syncthreads();
  if (t == 0){
    float W0=0,Wx=0,Wy=0,Wg=0;
    for (int k = 0; k < 4; k++){ W0+=red[k][0]; Wx+=red[k][1]; Wy+=red[k][2]; Wg+=red[k][3]; }
    // sum wts*d2 = Wg - (Wx^2+Wy^2)*(2 - W0)   (exact, since new_pos=(Wx,Wy))
    float s2 = Wg - (Wx*Wx + Wy*Wy)*(2.f - W0);
    psout[bs*3+0] = Wx; psout[bs*3+1] = Wy; psout[bs*3+2] = sqrtf(fmaxf(s2, 0.f));
  }
}

// ---------------- GRU cell --------------------------------------------------
__global__ void k_gru(const float* __restrict__ upd, float* __restrict__ queries,
                      const float* __restrict__ wih, const float* __restrict__ whh,
                      const float* __restrict__ bih, const float* __restrict__ bhh){
  int row = blockIdx.x; int t = threadIdx.x;   // 112 x 192
  __shared__ float xs[64], hs[64], gis[192], ghs[192];
  if (t < 64){ xs[t] = upd[row*64 + t]; hs[t] = queries[row*64 + t]; }
  __syncthreads();
  float gi = bih[t], gh = bhh[t];
  for (int e = 0; e < 64; e++){
    gi = fmaf(wih[t*64 + e], xs[e], gi);
    gh = fmaf(whh[t*64 + e], hs[e], gh);
  }
  gis[t] = gi; ghs[t] = gh;
  __syncthreads();
  if (t < 64){
    float r = 1.0f/(1.0f + expf(-(gis[t]      + ghs[t])));
    float z = 1.0f/(1.0f + expf(-(gis[64+t]   + ghs[64+t])));
    float n = tanhf(gis[128+t] + r*ghs[128+t]);
    queries[row*64 + t] = (1.0f - z)*n + z*hs[t];
  }
}

// ---------------- heads: alpha, slot_feat, copy queries --------------------
__global__ void k_final(const float* __restrict__ queries, const float* __restrict__ nps,
                        const float* __restrict__ a1w, const float* __restrict__ a1b,
                        const float* __restrict__ a2w, const float* __restrict__ a2b,
                        const float* __restrict__ f1w, const float* __restrict__ f1b,
                        const float* __restrict__ f2w, const float* __restrict__ f2b,
                        float* __restrict__ out){
  int bs = blockIdx.x; int e = threadIdx.x;    // 112 x 64
  __shared__ float qs[64], hf[64], ha[32];
  float q = queries[bs*64 + e];
  qs[e] = q;
  out[bs*64 + e] = q;                           // queries output at offset 0
  __syncthreads();
  float accf = f1b[e];
  for (int i = 0; i < 64; i++) accf = fmaf(qs[i], f1w[i*64 + e], accf);
  hf[e] = fmaxf(accf, 0.f);
  if (e < 32){
    float acca = a1b[e];
    for (int i = 0; i < 64; i++) acca = fmaf(qs[i], a1w[i*32 + e], acca);
    ha[e] = fmaxf(acca, 0.f);
  }
  __syncthreads();
  if (e < 3){
    float sf = f2b[e];
    for (int o = 0; o < 64; o++) sf = fmaf(hf[o], f2w[o*3 + e], sf);
    out[465920 + bs*3 + e] = sf + nps[bs*3 + e];   // slot_feat
  }
  if (e == 32){
    float al = a2b[0];
    for (int o = 0; o < 32; o++) al = fmaf(ha[o], a2w[o], al);
    out[466256 + bs] = 1.0f/(1.0f + expf(-al));    // alpha
  }
}

// ---------------------------------------------------------------------------
extern "C" void kernel_launch(void* const* d_in, const int* in_sizes, int n_in,
                              void* d_out, int out_size, void* d_ws, size_t ws_size,
                              hipStream_t stream){
  const float* data        = (const float*)d_in[0];
  const float* slot_noise  = (const float*)d_in[1];
  const float* pos_rand    = (const float*)d_in[2];
  const float* conv0_w     = (const float*)d_in[3];
  const float* conv0_b     = (const float*)d_in[4];
  const float* conv1_w     = (const float*)d_in[5];
  const float* conv1_b     = (const float*)d_in[6];
  const float* conv2_w     = (const float*)d_in[7];
  const float* conv2_b     = (const float*)d_in[8];
  const float* dataN_g     = (const float*)d_in[9];
  const float* dataN_b     = (const float*)d_in[10];
  const float* queryN_g    = (const float*)d_in[11];
  const float* queryN_b    = (const float*)d_in[12];
  const float* toK_w       = (const float*)d_in[13];
  const float* toK_b       = (const float*)d_in[14];
  const float* toV_w       = (const float*)d_in[15];
  const float* toV_b       = (const float*)d_in[16];
  const float* dense_w     = (const float*)d_in[17];
  const float* dense_b     = (const float*)d_in[18];
  const float* mlp1_w      = (const float*)d_in[19];
  const float* mlp1_b      = (const float*)d_in[20];
  const float* mlp2_w      = (const float*)d_in[21];
  const float* mlp2_b      = (const float*)d_in[22];
  const float* gru_wih     = (const float*)d_in[23];
  const float* gru_whh     = (const float*)d_in[24];
  const float* gru_bih     = (const float*)d_in[25];
  const float* gru_bhh     = (const float*)d_in[26];
  const float* alpha1_w    = (const float*)d_in[27];
  const float* alpha1_b    = (const float*)d_in[28];
  const float* alpha2_w    = (const float*)d_in[29];
  const float* alpha2_b    = (const float*)d_in[30];
  const float* final1_w    = (const float*)d_in[31];
  const float* final1_b    = (const float*)d_in[32];
  const float* final2_w    = (const float*)d_in[33];
  const float* final2_b    = (const float*)d_in[34];
  const float* slots_mu    = (const float*)d_in[35];
  const float* slots_lsig  = (const float*)d_in[36];

  float* ws   = (float*)d_ws;
  float* bufA = ws;                    // 4,194,304 : conv0 out -> conv2 out -> encK
  float* bufB = bufA + 4194304;        // 4,194,304 : conv1 out -> enc
  float* encV = bufB + 4194304;        // 4,194,304
  float* wt1  = encV + 4194304;        // 102,400
  float* wt2  = wt1 + 102400;          // 102,400
  float* attw = wt2 + 102400;          // 458,752 (logits/att, iters 0-2)
  float* queries = attw + 458752;      // 7,168
  float* qln  = queries + 7168;        // 7,168
  float* ps   = qln + 7168;            // 512 (pos_scale, 336 used)
  float* absc = ps + 512;              // 21,504 (A/B/cc per (b,s))
  float* sum_att = absc + 21504;       // 128
  float* upd  = sum_att + 128;         // 7,168
  float* nps  = upd + 7168;            // 512
  // total ~13.3M floats ~= 53 MB

  float* outq   = (float*)d_out;       // queries [112*64]
  float* outatt = outq + 7168;         // att [16*7*4096]

  k_prep<<<112, 64, 0, stream>>>(slot_noise, pos_rand, slots_mu, slots_lsig, queries, ps);
  k_conv0<<<1024, 256, 0, stream>>>(data, conv0_w, conv0_b, bufA);
  k_wtrans<<<400, 256, 0, stream>>>(conv1_w, wt1);
  k_wtrans<<<400, 256, 0, stream>>>(conv2_w, wt2);
  k_conv<<<1024, 256, 0, stream>>>(bufA, wt1, conv1_b, bufB);
  k_conv<<<1024, 256, 0, stream>>>(bufB, wt2, conv2_b, bufA);
  k_encln<<<1024, 256, 0, stream>>>(bufA, dataN_g, dataN_b, bufB);
  k_proj<<<1024, 256, 0, stream>>>(bufB, toK_w, toK_b, toV_w, toV_b, bufA, encV);
  float* encK = bufA;

  for (int p = 0; p < 4; p++){
    float* attp = (p == 3) ? outatt : attw;
    k_phaseprep<<<112, 64, 0, stream>>>(queries, ps, queryN_g, queryN_b, dense_w, dense_b,
                                        qln, absc, sum_att, upd);
    k_kv<<<7168, 256, 0, stream>>>(encK, mlp1_w, mlp1_b, mlp2_w, mlp2_b, queryN_g, queryN_b,
                                   absc, qln, attp, sum_att, attp, 0);
    k_softmax<<<256, 256, 0, stream>>>(attp, sum_att);
    k_frames<<<112, 256, 0, stream>>>(attp, sum_att, (p == 3) ? nps : ps);
    if (p < 3){
      k_kv<<<7168, 256, 0, stream>>>(encV, mlp1_w, mlp1_b, mlp2_w, mlp2_b, queryN_g, queryN_b,
                                     absc, qln, attp, sum_att, upd, 1);
      k_gru<<<112, 192, 0, stream>>>(upd, queries, gru_wih, gru_whh, gru_bih, gru_bhh);
    }
  }
  k_final<<<112, 64, 0, stream>>>(queries, nps, alpha1_w, alpha1_b, alpha2_w, alpha2_b,
                                  final1_w, final1_b, final2_w, final2_b, outq);
}

// Round 2
// 958.949 us; speedup vs baseline: 2.9106x; 2.9106x over previous
//
#include <hip/hip_runtime.h>
#include <cmath>

// ---------------------------------------------------------------------------
// InvariantSlotAttention forward. R2: heavy pass (k_kv) rewritten as bf16
// MFMA (16x16x32) with W2 folded out of the inner loop:
//   K-pass: logit = (relu(X@W1+b1) . w2q + b2.q) * 0.125, w2q = W2 @ q_ln
//   V-pass: upd   = (sum_d w_d relu(Y_d)) @ W2 + (sum w) b2   (W2 applied in k_gru)
// B=16, S=7, E=HID=64, D=4096, N_ITER=3, TSOFT=0.125
// ---------------------------------------------------------------------------

#define RLOW_F 0.1f
#define RHIGH_F 0.22360679774997896f

typedef __attribute__((ext_vector_type(8))) __bf16 bf16x8;
typedef __attribute__((ext_vector_type(4))) float f32x4;

__device__ __forceinline__ float wsum64(float v){
  #pragma unroll
  for (int off = 32; off > 0; off >>= 1) v += __shfl_xor(v, off, 64);
  return v;
}
__device__ __forceinline__ float rdlane(float v, int l){
  return __int_as_float(__builtin_amdgcn_readlane(__float_as_int(v), l));
}

// ---------------- init: queries = mu + exp(logsig)*noise ; pos_scale -------
__global__ void k_prep(const float* __restrict__ noise, const float* __restrict__ prand,
                       const float* __restrict__ mu, const float* __restrict__ logsig,
                       float* __restrict__ queries, float* __restrict__ ps){
  int row = blockIdx.x;            // b*7+s, 112 blocks
  int e = threadIdx.x;             // 64
  int s = row % 7;
  queries[row*64 + e] = mu[e] + expf(logsig[e]) * noise[row*64 + e];
  if (e < 3){
    float pr = prand[row*3 + e];
    float v;
    if (s < 2)      v = pr - 0.5f;                      // source indexes slot dim
    else if (s == 6) v = (RLOW_F - RHIGH_F)*pr + RHIGH_F;
    else            v = pr;
    ps[row*3 + e] = v;
  }
}

// ---------------- conv0: 1->64 channels, 5x5 same, relu ---------------------
__global__ __launch_bounds__(256) void k_conv0(const float* __restrict__ in,
                        const float* __restrict__ w, const float* __restrict__ bias,
                        float* __restrict__ out){
  int bi = blockIdx.x; int b = bi >> 6; int y = bi & 63;   // 1024 blocks
  int t = threadIdx.x; int lane = t & 63; int xg = t >> 6;
  __shared__ float s_in[5*68];
  __shared__ float s_w[64*25];
  __shared__ float s_out[64*65];
  for (int i = t; i < 1600; i += 256) s_w[i] = w[i];
  for (int i = t; i < 340; i += 256){
    int r = i / 68, cx = i % 68;
    int yy = y + r - 2, gx = cx - 2;
    float v = 0.f;
    if (yy >= 0 && yy < 64 && gx >= 0 && gx < 64) v = in[(b*64 + yy)*64 + gx];
    s_in[r*68 + cx] = v;
  }
  __syncthreads();
  int o = lane;
  float bv = bias[o];
  float acc[16];
  #pragma unroll
  for (int k = 0; k < 16; k++) acc[k] = bv;
  #pragma unroll
  for (int ky = 0; ky < 5; ky++){
    float rv[20];
    const float4* p = reinterpret_cast<const float4*>(&s_in[ky*68 + xg*16]);
    #pragma unroll
    for (int q = 0; q < 5; q++){ float4 f = p[q]; rv[q*4]=f.x; rv[q*4+1]=f.y; rv[q*4+2]=f.z; rv[q*4+3]=f.w; }
    #pragma unroll
    for (int kx = 0; kx < 5; kx++){
      float wv = s_w[o*25 + ky*5 + kx];
      #pragma unroll
      for (int k = 0; k < 16; k++) acc[k] = fmaf(rv[k+kx], wv, acc[k]);
    }
  }
  #pragma unroll
  for (int k = 0; k < 16; k++) s_out[o*65 + xg*16 + k] = fmaxf(acc[k], 0.f);
  __syncthreads();
  #pragma unroll
  for (int k = 0; k < 16; k++){
    int oo = xg + 4*k;
    out[((b*64 + oo)*64 + y)*64 + lane] = s_out[oo*65 + lane];
  }
}

// ---------------- weight transpose [o][c][ky][kx] -> [c][ky][kx][o] --------
__global__ void k_wtrans(const float* __restrict__ w, float* __restrict__ wt){
  int idx = blockIdx.x*256 + threadIdx.x;
  if (idx >= 102400) return;
  int o = idx / 1600; int rem = idx % 1600;  // rem = c*25 + ky*5 + kx
  wt[rem*64 + o] = w[idx];
}

// ---------------- conv1/conv2: 64->64 channels, 5x5 same, relu -------------
__global__ __launch_bounds__(256) void k_conv(const float* __restrict__ in,
                       const float* __restrict__ wt, const float* __restrict__ bias,
                       float* __restrict__ out){
  int bi = blockIdx.x; int b = bi >> 6; int y = bi & 63;
  int t = threadIdx.x; int lane = t & 63; int xg = t >> 6;
  __shared__ float s_in[16*5*68];
  __shared__ float s_out[64*65];
  int o = lane;
  float bv = bias[o];
  float acc[16];
  #pragma unroll
  for (int k = 0; k < 16; k++) acc[k] = bv;
  for (int cc0 = 0; cc0 < 64; cc0 += 16){
    __syncthreads();
    for (int rid = xg; rid < 80; rid += 4){
      int c = rid / 5, r = rid % 5;
      int yy = y + r - 2;
      float v = 0.f;
      if (yy >= 0 && yy < 64) v = in[((b*64 + cc0 + c)*64 + yy)*64 + lane];
      s_in[(c*5+r)*68 + lane + 2] = v;
      if (lane < 2)   s_in[(c*5+r)*68 + lane] = 0.f;
      if (lane >= 62) s_in[(c*5+r)*68 + lane + 4] = 0.f;
    }
    __syncthreads();
    for (int c = 0; c < 16; c++){
      #pragma unroll
      for (int ky = 0; ky < 5; ky++){
        float rv[20];
        const float4* p = reinterpret_cast<const float4*>(&s_in[(c*5+ky)*68 + xg*16]);
        #pragma unroll
        for (int q = 0; q < 5; q++){ float4 f = p[q]; rv[q*4]=f.x; rv[q*4+1]=f.y; rv[q*4+2]=f.z; rv[q*4+3]=f.w; }
        const float* wp = &wt[((cc0+c)*25 + ky*5)*64 + o];
        float wv[5];
        #pragma unroll
        for (int kx = 0; kx < 5; kx++) wv[kx] = wp[kx*64];
        #pragma unroll
        for (int kx = 0; kx < 5; kx++){
          #pragma unroll
          for (int k = 0; k < 16; k++) acc[k] = fmaf(rv[k+kx], wv[kx], acc[k]);
        }
      }
    }
  }
  __syncthreads();
  #pragma unroll
  for (int k = 0; k < 16; k++) s_out[o*65 + xg*16 + k] = fmaxf(acc[k], 0.f);
  __syncthreads();
  #pragma unroll
  for (int k = 0; k < 16; k++){
    int oo = xg + 4*k;
    out[((b*64 + oo)*64 + y)*64 + lane] = s_out[oo*65 + lane];
  }
}

// ---------------- NCHW -> [b][d][c] + LayerNorm(dataN) ---------------------
__global__ __launch_bounds__(256) void k_encln(const float* __restrict__ in,
                        const float* __restrict__ g, const float* __restrict__ be,
                        float* __restrict__ enc){
  int bi = blockIdx.x; int b = bi >> 6; int y = bi & 63;
  int t = threadIdx.x; int lane = t & 63; int w = t >> 6;
  __shared__ float tile[64*65];
  for (int k = 0; k < 16; k++){
    int c = w + 4*k;
    tile[c*65 + lane] = in[((b*64 + c)*64 + y)*64 + lane];
  }
  __syncthreads();
  float gv = g[lane], bb = be[lane];
  for (int k = 0; k < 16; k++){
    int x = w*16 + k;
    float v = tile[lane*65 + x];            // lane = channel
    float m = wsum64(v) * (1.f/64.f);
    float d = v - m;
    float var = wsum64(d*d) * (1.f/64.f);
    float ov = d * (1.0f/sqrtf(var + 1e-5f)) * gv + bb;
    enc[(b*4096 + y*64 + x)*64 + lane] = ov;
  }
}

// ---------------- enc @ toK_w , enc @ toV_w --------------------------------
__global__ __launch_bounds__(256) void k_proj(const float* __restrict__ enc,
                       const float* __restrict__ wk, const float* __restrict__ bk,
                       const float* __restrict__ wv, const float* __restrict__ bvp,
                       float* __restrict__ K, float* __restrict__ V){
  int bi = blockIdx.x; int b = bi >> 6; int tile = bi & 63;  // 1024 blocks
  int t = threadIdx.x; int j = t & 63; int w = t >> 6;
  __shared__ float W1[4096];
  __shared__ float W2[4096];
  for (int i = t; i < 4096; i += 256){ W1[i] = wk[i]; W2[i] = wv[i]; }
  int d0 = tile*64 + w*16;
  float x[16];
  #pragma unroll
  for (int r = 0; r < 16; r++) x[r] = enc[(b*4096 + d0 + r)*64 + j];
  __syncthreads();
  float aK[16], aV[16];
  float bkv = bk[j], bvv = bvp[j];
  #pragma unroll
  for (int r = 0; r < 16; r++){ aK[r] = bkv; aV[r] = bvv; }
  for (int i = 0; i < 64; i++){
    float w1 = W1[i*64 + j], w2 = W2[i*64 + j];
    #pragma unroll
    for (int r = 0; r < 16; r++){
      float xv = rdlane(x[r], i);
      aK[r] = fmaf(xv, w1, aK[r]);
      aV[r] = fmaf(xv, w2, aV[r]);
    }
  }
  #pragma unroll
  for (int r = 0; r < 16; r++){
    K[(b*4096 + d0 + r)*64 + j] = aK[r];
    V[(b*4096 + d0 + r)*64 + j] = aV[r];
  }
}

// ---------------- pack W1 (f32 [k][n]) into B-fragment-ordered bf16 --------
// frag f = ks*4+nt; lane l = q*16+cr; element j: W1[ks*32+q*8+j][nt*16+cr]
__global__ void k_packw1(const float* __restrict__ w1, unsigned short* __restrict__ out){
  int idx = blockIdx.x*256 + threadIdx.x;   // 4096
  int jj = idx & 7;
  int lane = (idx >> 3) & 63;
  int frag = idx >> 9;                      // 0..7
  int ks = frag >> 2, nt = frag & 3;
  int q = lane >> 4, cr = lane & 15;
  int k = ks*32 + q*8 + jj;
  int n = nt*16 + cr;
  __bf16 h = (__bf16)w1[k*64 + n];
  out[idx] = *reinterpret_cast<unsigned short*>(&h);
}

// ---------------- per-phase prep: LN(queries), A/B/cc, w2q, zero accs ------
__global__ void k_phaseprep(const float* __restrict__ queries, const float* __restrict__ ps,
                            const float* __restrict__ qg_, const float* __restrict__ qb_,
                            const float* __restrict__ dw, const float* __restrict__ db,
                            const float* __restrict__ mlp2w, const float* __restrict__ mlp2b,
                            float* __restrict__ absc, float* __restrict__ w2qc,
                            float* __restrict__ sum_att, float* __restrict__ upd){
  int row = blockIdx.x; int e = threadIdx.x;   // 112 x 64
  float q = queries[row*64 + e];
  float m = wsum64(q) * (1.f/64.f);
  float d = q - m;
  float var = wsum64(d*d) * (1.f/64.f);
  float qlnv = d * (1.0f/sqrtf(var + 1e-5f)) * qg_[e] + qb_[e];
  float px = ps[row*3], py = ps[row*3+1], sc = ps[row*3+2];
  float A  = dw[e]      / sc;
  float Bv = dw[64 + e] / sc;
  absc[(row*3+0)*64 + e] = A;
  absc[(row*3+1)*64 + e] = Bv;
  absc[(row*3+2)*64 + e] = db[e] - px*A - py*Bv;
  // w2q[i=e] = sum_j W2[i][j] * qln[j] ; c2 = b2 . qln
  float acc = 0.f;
  const float* wrow = mlp2w + e*64;
  for (int j = 0; j < 64; j++) acc = fmaf(wrow[j], rdlane(qlnv, j), acc);
  w2qc[row*68 + e] = acc;
  float c2 = wsum64(mlp2b[e] * qlnv);
  if (e == 0) w2qc[row*68 + 64] = c2;
  upd[row*64 + e] = 0.f;
  if (e == 0) sum_att[row] = 0.f;
}

// ---------------- heavy pass: bf16 MFMA GEMM1 + fused epilogue -------------
// mode 0: outp = logits [B,S,D]; mode 1: outp = upd_pre [B,S,64] (atomic)
__global__ __launch_bounds__(256) void k_attn(const float* __restrict__ encX,
     const unsigned short* __restrict__ w1pack, const float* __restrict__ mlp1b,
     const float* __restrict__ absc, const float* __restrict__ qg_,
     const float* __restrict__ qb_, const float* __restrict__ w2qc,
     const float* __restrict__ att, const float* __restrict__ sum_att,
     float* __restrict__ outp, int mode){
  int t = threadIdx.x; int wv = t >> 6; int l = t & 63;
  int q = l >> 4, cr = l & 15;
  int bs = blockIdx.x >> 6; int tile = blockIdx.x & 63;   // 7168 blocks
  int b = bs / 7;
  int m0 = tile*64 + wv*16;           // this wave's 16-row m-tile
  int drow = m0 + cr;                 // lane's row for A-fragment build

  // B fragments of W1 (prepacked, coalesced 16B loads)
  const bf16x8* wp = reinterpret_cast<const bf16x8*>(w1pack);
  bf16x8 Bf[8];
  #pragma unroll
  for (int f = 0; f < 8; f++) Bf[f] = wp[f*64 + l];

  // build X row in A-layout: lane holds row drow, features {q*8..+7, 32+q*8..+7}
  const float* Ac = absc + bs*192;
  const float* er = encX + (size_t)(b*4096 + drow)*64;
  float gx = -0.5f + (float)(drow & 63) * (1.f/63.f);
  float gy = -0.5f + (float)((drow >> 6) & 63) * (1.f/63.f);
  float x[16];
  #pragma unroll
  for (int h = 0; h < 2; h++){
    int fb = h ? (32 + q*8) : (q*8);
    const float4* e4 = reinterpret_cast<const float4*>(er + fb);
    const float4* A4 = reinterpret_cast<const float4*>(Ac + fb);
    const float4* B4 = reinterpret_cast<const float4*>(Ac + 64 + fb);
    const float4* C4 = reinterpret_cast<const float4*>(Ac + 128 + fb);
    #pragma unroll
    for (int p = 0; p < 2; p++){
      float4 e = e4[p], Av = A4[p], Bv = B4[p], Cv = C4[p];
      int o = h*8 + p*4;
      x[o+0] = e.x + gx*Av.x + gy*Bv.x + Cv.x;
      x[o+1] = e.y + gx*Av.y + gy*Bv.y + Cv.y;
      x[o+2] = e.z + gx*Av.z + gy*Bv.z + Cv.z;
      x[o+3] = e.w + gx*Av.w + gy*Bv.w + Cv.w;
    }
  }
  // LN over the row (16 feats/lane x 4 quads): cross-quad shuffles only
  float s = 0.f;
  #pragma unroll
  for (int k = 0; k < 16; k++) s += x[k];
  s += __shfl_xor(s, 16, 64); s += __shfl_xor(s, 32, 64);
  float m = s * (1.f/64.f);
  float v = 0.f;
  #pragma unroll
  for (int k = 0; k < 16; k++){ float dd = x[k] - m; v += dd*dd; }
  v += __shfl_xor(v, 16, 64); v += __shfl_xor(v, 32, 64);
  float rstd = 1.0f/sqrtf(v * (1.f/64.f) + 1e-5f);

  bf16x8 a0, a1;
  #pragma unroll
  for (int h = 0; h < 2; h++){
    int fb = h ? (32 + q*8) : (q*8);
    const float4* g4 = reinterpret_cast<const float4*>(qg_ + fb);
    const float4* b4 = reinterpret_cast<const float4*>(qb_ + fb);
    #pragma unroll
    for (int p = 0; p < 2; p++){
      float4 gg = g4[p], bb = b4[p];
      int o = h*8 + p*4;
      float r0 = (x[o+0]-m)*rstd*gg.x + bb.x;
      float r1 = (x[o+1]-m)*rstd*gg.y + bb.y;
      float r2 = (x[o+2]-m)*rstd*gg.z + bb.z;
      float r3 = (x[o+3]-m)*rstd*gg.w + bb.w;
      if (h == 0){ a0[p*4+0]=(__bf16)r0; a0[p*4+1]=(__bf16)r1; a0[p*4+2]=(__bf16)r2; a0[p*4+3]=(__bf16)r3; }
      else       { a1[p*4+0]=(__bf16)r0; a1[p*4+1]=(__bf16)r1; a1[p*4+2]=(__bf16)r2; a1[p*4+3]=(__bf16)r3; }
    }
  }

  // GEMM1: Y[16 rows][64 cols] per wave; D: col=cr, row=q*4+reg
  f32x4 zero = {0.f, 0.f, 0.f, 0.f};
  f32x4 acc[4];
  #pragma unroll
  for (int nt = 0; nt < 4; nt++){
    acc[nt] = __builtin_amdgcn_mfma_f32_16x16x32_bf16(a0, Bf[nt],     zero,    0, 0, 0);
    acc[nt] = __builtin_amdgcn_mfma_f32_16x16x32_bf16(a1, Bf[4 + nt], acc[nt], 0, 0, 0);
  }

  if (mode == 0){
    const float* wq = w2qc + bs*68;
    float c2 = wq[64];
    float p[4] = {0.f, 0.f, 0.f, 0.f};
    #pragma unroll
    for (int nt = 0; nt < 4; nt++){
      float bb  = mlp1b[nt*16 + cr];
      float wqv = wq[nt*16 + cr];
      #pragma unroll
      for (int reg = 0; reg < 4; reg++){
        float y = fmaxf(acc[nt][reg] + bb, 0.f);
        p[reg] = fmaf(y, wqv, p[reg]);
      }
    }
    #pragma unroll
    for (int reg = 0; reg < 4; reg++){
      #pragma unroll
      for (int off = 1; off < 16; off <<= 1) p[reg] += __shfl_xor(p[reg], off, 64);
    }
    if (cr == 0){
      #pragma unroll
      for (int reg = 0; reg < 4; reg++)
        outp[bs*4096 + m0 + q*4 + reg] = (p[reg] + c2) * 0.125f;
    }
  } else {
    float sa = sum_att[bs];
    float wr[4];
    #pragma unroll
    for (int reg = 0; reg < 4; reg++)
      wr[reg] = att[bs*4096 + m0 + q*4 + reg] / sa + 1e-8f;
    float pc[4] = {0.f, 0.f, 0.f, 0.f};
    #pragma unroll
    for (int nt = 0; nt < 4; nt++){
      float bb = mlp1b[nt*16 + cr];
      #pragma unroll
      for (int reg = 0; reg < 4; reg++)
        pc[nt] = fmaf(wr[reg], fmaxf(acc[nt][reg] + bb, 0.f), pc[nt]);
    }
    #pragma unroll
    for (int nt = 0; nt < 4; nt++){
      pc[nt] += __shfl_xor(pc[nt], 16, 64);
      pc[nt] += __shfl_xor(pc[nt], 32, 64);
    }
    __shared__ float red[4][64];
    if (q == 0){
      #pragma unroll
      for (int nt = 0; nt < 4; nt++) red[wv][nt*16 + cr] = pc[nt];
    }
    __syncthreads();
    if (t < 64) atomicAdd(&outp[bs*64 + t], red[0][t] + red[1][t] + red[2][t] + red[3][t]);
  }
}

// ---------------- softmax over slots (axis=1) + per-(b,s) sums -------------
__global__ void k_softmax(float* __restrict__ att, float* __restrict__ sum_att){
  int bi = blockIdx.x;                 // 256 = B * (D/256)
  int b = bi >> 4;
  int t = threadIdx.x;
  int d = (bi & 15)*256 + t;
  int lane = t & 63; int w = t >> 6;
  __shared__ float red[4];
  float l[7];
  #pragma unroll
  for (int s = 0; s < 7; s++) l[s] = att[(b*7+s)*4096 + d];
  float m = l[0];
  #pragma unroll
  for (int s = 1; s < 7; s++) m = fmaxf(m, l[s]);
  float sum = 0.f;
  #pragma unroll
  for (int s = 0; s < 7; s++){ l[s] = expf(l[s] - m); sum += l[s]; }
  for (int s = 0; s < 7; s++){
    float a = l[s] / sum;
    att[(b*7+s)*4096 + d] = a;
    float ws = wsum64(a);
    if (lane == 0) red[w] = ws;
    __syncthreads();
    if (t == 0) atomicAdd(&sum_att[b*7+s], red[0]+red[1]+red[2]+red[3]);
    __syncthreads();
  }
}

// ---------------- update_frames + sumw -------------------------------------
__global__ void k_frames(const float* __restrict__ att, const float* __restrict__ sum_att,
                         float* __restrict__ psout, float* __restrict__ sumw){
  int bs = blockIdx.x; int t = threadIdx.x;   // 112 x 256
  float sa = sum_att[bs];
  float a0 = 0.f, ax = 0.f, ay = 0.f, a2 = 0.f;
  for (int d = t; d < 4096; d += 256){
    float wv = att[bs*4096 + d] / sa + 1e-8f;
    float gx = -0.5f + (float)(d & 63) * (1.f/63.f);
    float gy = -0.5f + (float)(d >> 6) * (1.f/63.f);
    a0 += wv; ax += wv*gx; ay += wv*gy; a2 += wv*(gx*gx + gy*gy);
  }
  __shared__ float red[4][4];
  int lane = t & 63, w = t >> 6;
  a0 = wsum64(a0); ax = wsum64(ax); ay = wsum64(ay); a2 = wsum64(a2);
  if (lane == 0){ red[w][0]=a0; red[w][1]=ax; red[w][2]=ay; red[w][3]=a2; }
  __syncthreads();
  if (t == 0){
    float W0=0,Wx=0,Wy=0,Wg=0;
    for (int k = 0; k < 4; k++){ W0+=red[k][0]; Wx+=red[k][1]; Wy+=red[k][2]; Wg+=red[k][3]; }
    // sum wts*d2 = Wg - (Wx^2+Wy^2)*(2 - W0)   (exact, since new_pos=(Wx,Wy))
    float s2 = Wg - (Wx*Wx + Wy*Wy)*(2.f - W0);
    psout[bs*3+0] = Wx; psout[bs*3+1] = Wy; psout[bs*3+2] = sqrtf(fmaxf(s2, 0.f));
    sumw[bs] = W0;
  }
}

// ---------------- GRU cell (applies folded W2 to upd_pre first) ------------
__global__ void k_gru(const float* __restrict__ upd, float* __restrict__ queries,
                      const float* __restrict__ wih, const float* __restrict__ whh,
                      const float* __restrict__ bih, const float* __restrict__ bhh,
                      const float* __restrict__ mlp2w, const float* __restrict__ mlp2b,
                      const float* __restrict__ sumw){
  int row = blockIdx.x; int t = threadIdx.x;   // 112 x 192
  __shared__ float us[64], hs[64], xs[64], gis[192], ghs[192];
  if (t < 64){ us[t] = upd[row*64 + t]; hs[t] = queries[row*64 + t]; }
  __syncthreads();
  if (t < 64){
    float a = sumw[row] * mlp2b[t];
    for (int i = 0; i < 64; i++) a = fmaf(us[i], mlp2w[i*64 + t], a);
    xs[t] = a;
  }
  __syncthreads();
  float gi = bih[t], gh = bhh[t];
  for (int e = 0; e < 64; e++){
    gi = fmaf(wih[t*64 + e], xs[e], gi);
    gh = fmaf(whh[t*64 + e], hs[e], gh);
  }
  gis[t] = gi; ghs[t] = gh;
  __syncthreads();
  if (t < 64){
    float r = 1.0f/(1.0f + expf(-(gis[t]      + ghs[t])));
    float z = 1.0f/(1.0f + expf(-(gis[64+t]   + ghs[64+t])));
    float n = tanhf(gis[128+t] + r*ghs[128+t]);
    queries[row*64 + t] = (1.0f - z)*n + z*hs[t];
  }
}

// ---------------- heads: alpha, slot_feat, copy queries --------------------
__global__ void k_final(const float* __restrict__ queries, const float* __restrict__ nps,
                        const float* __restrict__ a1w, const float* __restrict__ a1b,
                        const float* __restrict__ a2w, const float* __restrict__ a2b,
                        const float* __restrict__ f1w, const float* __restrict__ f1b,
                        const float* __restrict__ f2w, const float* __restrict__ f2b,
                        float* __restrict__ out){
  int bs = blockIdx.x; int e = threadIdx.x;    // 112 x 64
  __shared__ float qs[64], hf[64], ha[32];
  float q = queries[bs*64 + e];
  qs[e] = q;
  out[bs*64 + e] = q;                           // queries output at offset 0
  __syncthreads();
  float accf = f1b[e];
  for (int i = 0; i < 64; i++) accf = fmaf(qs[i], f1w[i*64 + e], accf);
  hf[e] = fmaxf(accf, 0.f);
  if (e < 32){
    float acca = a1b[e];
    for (int i = 0; i < 64; i++) acca = fmaf(qs[i], a1w[i*32 + e], acca);
    ha[e] = fmaxf(acca, 0.f);
  }
  __syncthreads();
  if (e < 3){
    float sf = f2b[e];
    for (int o = 0; o < 64; o++) sf = fmaf(hf[o], f2w[o*3 + e], sf);
    out[465920 + bs*3 + e] = sf + nps[bs*3 + e];   // slot_feat
  }
  if (e == 32){
    float al = a2b[0];
    for (int o = 0; o < 32; o++) al = fmaf(ha[o], a2w[o], al);
    out[466256 + bs] = 1.0f/(1.0f + expf(-al));    // alpha
  }
}

// ---------------------------------------------------------------------------
extern "C" void kernel_launch(void* const* d_in, const int* in_sizes, int n_in,
                              void* d_out, int out_size, void* d_ws, size_t ws_size,
                              hipStream_t stream){
  const float* data        = (const float*)d_in[0];
  const float* slot_noise  = (const float*)d_in[1];
  const float* pos_rand    = (const float*)d_in[2];
  const float* conv0_w     = (const float*)d_in[3];
  const float* conv0_b     = (const float*)d_in[4];
  const float* conv1_w     = (const float*)d_in[5];
  const float* conv1_b     = (const float*)d_in[6];
  const float* conv2_w     = (const float*)d_in[7];
  const float* conv2_b     = (const float*)d_in[8];
  const float* dataN_g     = (const float*)d_in[9];
  const float* dataN_b     = (const float*)d_in[10];
  const float* queryN_g    = (const float*)d_in[11];
  const float* queryN_b    = (const float*)d_in[12];
  const float* toK_w       = (const float*)d_in[13];
  const float* toK_b       = (const float*)d_in[14];
  const float* toV_w       = (const float*)d_in[15];
  const float* toV_b       = (const float*)d_in[16];
  const float* dense_w     = (const float*)d_in[17];
  const float* dense_b     = (const float*)d_in[18];
  const float* mlp1_w      = (const float*)d_in[19];
  const float* mlp1_b      = (const float*)d_in[20];
  const float* mlp2_w      = (const float*)d_in[21];
  const float* mlp2_b      = (const float*)d_in[22];
  const float* gru_wih     = (const float*)d_in[23];
  const float* gru_whh     = (const float*)d_in[24];
  const float* gru_bih     = (const float*)d_in[25];
  const float* gru_bhh     = (const float*)d_in[26];
  const float* alpha1_w    = (const float*)d_in[27];
  const float* alpha1_b    = (const float*)d_in[28];
  const float* alpha2_w    = (const float*)d_in[29];
  const float* alpha2_b    = (const float*)d_in[30];
  const float* final1_w    = (const float*)d_in[31];
  const float* final1_b    = (const float*)d_in[32];
  const float* final2_w    = (const float*)d_in[33];
  const float* final2_b    = (const float*)d_in[34];
  const float* slots_mu    = (const float*)d_in[35];
  const float* slots_lsig  = (const float*)d_in[36];

  float* ws   = (float*)d_ws;
  float* bufA = ws;                    // 4,194,304 : conv0 out -> conv2 out -> encK
  float* bufB = bufA + 4194304;        // 4,194,304 : conv1 out -> enc
  float* encV = bufB + 4194304;        // 4,194,304
  float* wt1  = encV + 4194304;        // 102,400
  float* wt2  = wt1 + 102400;          // 102,400
  float* attw = wt2 + 102400;          // 458,752 (logits/att, iters 0-2)
  float* queries = attw + 458752;      // 7,168
  float* ps   = queries + 7168;        // 512 (pos_scale, 336 used)
  float* absc = ps + 512;              // 21,504 (A/B/cc per (b,s))
  float* sum_att = absc + 21504;       // 128
  float* upd  = sum_att + 128;         // 7,168 (upd_pre)
  float* nps  = upd + 7168;            // 512
  float* w2qc = nps + 512;             // 7,616 (112 x 68: w2q[64] + c2)
  float* sumw = w2qc + 7616;           // 128
  unsigned short* w1pack = (unsigned short*)(sumw + 128);   // 4096 bf16
  // total ~13.3M floats ~= 53.2 MB

  float* outq   = (float*)d_out;       // queries [112*64]
  float* outatt = outq + 7168;         // att [16*7*4096]

  k_prep<<<112, 64, 0, stream>>>(slot_noise, pos_rand, slots_mu, slots_lsig, queries, ps);
  k_packw1<<<16, 256, 0, stream>>>(mlp1_w, w1pack);
  k_conv0<<<1024, 256, 0, stream>>>(data, conv0_w, conv0_b, bufA);
  k_wtrans<<<400, 256, 0, stream>>>(conv1_w, wt1);
  k_wtrans<<<400, 256, 0, stream>>>(conv2_w, wt2);
  k_conv<<<1024, 256, 0, stream>>>(bufA, wt1, conv1_b, bufB);
  k_conv<<<1024, 256, 0, stream>>>(bufB, wt2, conv2_b, bufA);
  k_encln<<<1024, 256, 0, stream>>>(bufA, dataN_g, dataN_b, bufB);
  k_proj<<<1024, 256, 0, stream>>>(bufB, toK_w, toK_b, toV_w, toV_b, bufA, encV);
  float* encK = bufA;

  for (int p = 0; p < 4; p++){
    float* attp = (p == 3) ? outatt : attw;
    k_phaseprep<<<112, 64, 0, stream>>>(queries, ps, queryN_g, queryN_b, dense_w, dense_b,
                                        mlp2_w, mlp2_b, absc, w2qc, sum_att, upd);
    k_attn<<<7168, 256, 0, stream>>>(encK, w1pack, mlp1_b, absc, queryN_g, queryN_b,
                                     w2qc, attp, sum_att, attp, 0);
    k_softmax<<<256, 256, 0, stream>>>(attp, sum_att);
    k_frames<<<112, 256, 0, stream>>>(attp, sum_att, (p == 3) ? nps : ps, sumw);
    if (p < 3){
      k_attn<<<7168, 256, 0, stream>>>(encV, w1pack, mlp1_b, absc, queryN_g, queryN_b,
                                       w2qc, attp, sum_att, upd, 1);
      k_gru<<<112, 192, 0, stream>>>(upd, queries, gru_wih, gru_whh, gru_bih, gru_bhh,
                                     mlp2_w, mlp2_b, sumw);
    }
  }
  k_final<<<112, 64, 0, stream>>>(queries, nps, alpha1_w, alpha1_b, alpha2_w, alpha2_b,
                                  final1_w, final1_b, final2_w, final2_b, outq);
}

// Round 3
// 595.720 us; speedup vs baseline: 4.6852x; 1.6097x over previous
//
#include <hip/hip_runtime.h>
#include <cmath>

// ---------------------------------------------------------------------------
// InvariantSlotAttention forward. R3: conv1/conv2 as bf16 MFMA implicit-GEMM
// (NHWC, per-tap shifted LDS reads), LN fused into conv2 epilogue, K/V
// projection as bf16 MFMA. Heavy attention pass (k_attn) unchanged from R2.
// B=16, S=7, E=HID=64, D=4096, N_ITER=3, TSOFT=0.125
// ---------------------------------------------------------------------------

#define RLOW_F 0.1f
#define RHIGH_F 0.22360679774997896f

typedef __attribute__((ext_vector_type(8))) __bf16 bf16x8;
typedef __attribute__((ext_vector_type(4))) float f32x4;

__device__ __forceinline__ float wsum64(float v){
  #pragma unroll
  for (int off = 32; off > 0; off >>= 1) v += __shfl_xor(v, off, 64);
  return v;
}
__device__ __forceinline__ float rdlane(float v, int l){
  return __int_as_float(__builtin_amdgcn_readlane(__float_as_int(v), l));
}
__device__ __forceinline__ unsigned short bf16bits(float v){
  __bf16 h = (__bf16)v;
  return *reinterpret_cast<unsigned short*>(&h);
}

// ---------------- init: queries = mu + exp(logsig)*noise ; pos_scale -------
__global__ void k_prep(const float* __restrict__ noise, const float* __restrict__ prand,
                       const float* __restrict__ mu, const float* __restrict__ logsig,
                       float* __restrict__ queries, float* __restrict__ ps){
  int row = blockIdx.x;            // b*7+s, 112 blocks
  int e = threadIdx.x;             // 64
  int s = row % 7;
  queries[row*64 + e] = mu[e] + expf(logsig[e]) * noise[row*64 + e];
  if (e < 3){
    float pr = prand[row*3 + e];
    float v;
    if (s < 2)      v = pr - 0.5f;                      // source indexes slot dim
    else if (s == 6) v = (RLOW_F - RHIGH_F)*pr + RHIGH_F;
    else            v = pr;
    ps[row*3 + e] = v;
  }
}

// ---------------- conv0: 1->64 channels, 5x5 same, relu, NHWC bf16 out -----
__global__ __launch_bounds__(256) void k_conv0(const float* __restrict__ in,
                        const float* __restrict__ w, const float* __restrict__ bias,
                        unsigned short* __restrict__ out){
  int bi = blockIdx.x; int b = bi >> 6; int y = bi & 63;   // 1024 blocks
  int t = threadIdx.x; int lane = t & 63; int xg = t >> 6;
  __shared__ float s_in[5*68];
  __shared__ float s_w[64*25];
  __shared__ float s_out[64*65];
  for (int i = t; i < 1600; i += 256) s_w[i] = w[i];
  for (int i = t; i < 340; i += 256){
    int r = i / 68, cx = i % 68;
    int yy = y + r - 2, gx = cx - 2;
    float v = 0.f;
    if (yy >= 0 && yy < 64 && gx >= 0 && gx < 64) v = in[(b*64 + yy)*64 + gx];
    s_in[r*68 + cx] = v;
  }
  __syncthreads();
  int o = lane;
  float bv = bias[o];
  float acc[16];
  #pragma unroll
  for (int k = 0; k < 16; k++) acc[k] = bv;
  #pragma unroll
  for (int ky = 0; ky < 5; ky++){
    float rv[20];
    const float4* p = reinterpret_cast<const float4*>(&s_in[ky*68 + xg*16]);
    #pragma unroll
    for (int q = 0; q < 5; q++){ float4 f = p[q]; rv[q*4]=f.x; rv[q*4+1]=f.y; rv[q*4+2]=f.z; rv[q*4+3]=f.w; }
    #pragma unroll
    for (int kx = 0; kx < 5; kx++){
      float wv = s_w[o*25 + ky*5 + kx];
      #pragma unroll
      for (int k = 0; k < 16; k++) acc[k] = fmaf(rv[k+kx], wv, acc[k]);
    }
  }
  #pragma unroll
  for (int k = 0; k < 16; k++) s_out[o*65 + xg*16 + k] = fmaxf(acc[k], 0.f);
  __syncthreads();
  // write NHWC bf16: out[((b*64+y)*64 + px)*64 + ch]
  for (int i = t; i < 4096; i += 256){
    int px = i >> 6, ch = i & 63;
    out[((size_t)(b*64 + y)*64 + px)*64 + ch] = bf16bits(s_out[ch*65 + px]);
  }
}

// ---------------- pack conv weights [O][C][5][5] -> per-tap B-frag bf16 ----
// frag = (dy*10 + ks)*4 + nt ; lane l=q*16+cr ; elem j:
//   k = ks*32 + q*8 + j -> kx = k>>6, ch = k&63 ; n = nt*16+cr
__global__ void k_packconv(const float* __restrict__ w, unsigned short* __restrict__ out){
  int idx = blockIdx.x*256 + threadIdx.x;   // 102400
  if (idx >= 102400) return;
  int j = idx & 7;
  int l = (idx >> 3) & 63;
  int frag = idx >> 9;                      // 0..199
  int nt = frag & 3;
  int ks = (frag >> 2) % 10;
  int dy = frag / 40;
  int q = l >> 4, cr = l & 15;
  int k = ks*32 + q*8 + j;
  int kx = k >> 6, ch = k & 63;
  int n = nt*16 + cr;
  out[idx] = bf16bits(w[((n*64 + ch)*5 + dy)*5 + kx]);
}

// ---------------- conv1/conv2 as bf16 MFMA implicit GEMM -------------------
// mode 0: relu -> bf16 NHWC out. mode 1: relu -> LN(dataN) -> f32 NHWC enc.
__global__ __launch_bounds__(256) void k_convm(const unsigned short* __restrict__ in_bf,
                        const unsigned short* __restrict__ wpack,
                        const float* __restrict__ bias,
                        const float* __restrict__ lng, const float* __restrict__ lnb,
                        unsigned short* __restrict__ out_bf, float* __restrict__ out_f,
                        int mode){
  int bi = blockIdx.x;                  // 256 = 16 b * 16 ygroups
  int b = bi >> 4; int yg = bi & 15;
  int t = threadIdx.x; int wv = t >> 6; int l = t & 63;
  int q = l >> 4, cr = l & 15;
  int p0 = wv*16;

  // LDS: 8 rows x 68 px x (64ch bf16 + 16B pad) ; row stride 68*144=9792 B
  __shared__ char lds[8*68*144];

  // stage rows yg*4-2 .. yg*4+5 with zero halo (2 px each side)
  for (int ri = 0; ri < 8; ri++){
    int yy = yg*4 + ri - 2;
    bool rok = (yy >= 0 && yy < 64);
    const uint4* src = reinterpret_cast<const uint4*>(in_bf + (size_t)(b*64 + yy)*64*64);
    for (int i = t; i < 544; i += 256){          // 68 px * 8 16B-chunks
      int px = i >> 3, c8 = i & 7;
      uint4 v = {0u,0u,0u,0u};
      int gx = px - 2;
      if (rok && gx >= 0 && gx < 64) v = src[gx*8 + c8];
      *reinterpret_cast<uint4*>(&lds[ri*9792 + px*144 + c8*16]) = v;
    }
  }
  __syncthreads();

  f32x4 acc[4][4];                      // [row r][nt]
  #pragma unroll
  for (int r = 0; r < 4; r++)
    #pragma unroll
    for (int nt = 0; nt < 4; nt++) acc[r][nt] = (f32x4){0.f,0.f,0.f,0.f};

  const bf16x8* wp = reinterpret_cast<const bf16x8*>(wpack);
  for (int dy = 0; dy < 5; dy++){
    for (int ks = 0; ks < 10; ks++){
      bf16x8 Bf[4];
      int fbase = (dy*10 + ks)*4;
      #pragma unroll
      for (int nt = 0; nt < 4; nt++) Bf[nt] = wp[(fbase + nt)*64 + l];
      int aoff = (p0 + cr + (ks >> 1))*144 + (ks & 1)*64 + q*16;
      #pragma unroll
      for (int r = 0; r < 4; r++){
        bf16x8 a = *reinterpret_cast<const bf16x8*>(&lds[(r + dy)*9792 + aoff]);
        #pragma unroll
        for (int nt = 0; nt < 4; nt++)
          acc[r][nt] = __builtin_amdgcn_mfma_f32_16x16x32_bf16(a, Bf[nt], acc[r][nt], 0, 0, 0);
      }
    }
  }

  float bv[4];
  #pragma unroll
  for (int nt = 0; nt < 4; nt++) bv[nt] = bias[nt*16 + cr];

  if (mode == 0){
    // D: pixel = p0 + q*4 + reg, ch = nt*16 + cr
    #pragma unroll
    for (int r = 0; r < 4; r++){
      int y = yg*4 + r;
      #pragma unroll
      for (int reg = 0; reg < 4; reg++){
        int p = p0 + q*4 + reg;
        size_t base = ((size_t)(b*64 + y)*64 + p)*64;
        #pragma unroll
        for (int nt = 0; nt < 4; nt++)
          out_bf[base + nt*16 + cr] = bf16bits(fmaxf(acc[r][nt][reg] + bv[nt], 0.f));
      }
    }
  } else {
    float gv[4], bb[4];
    #pragma unroll
    for (int nt = 0; nt < 4; nt++){ gv[nt] = lng[nt*16 + cr]; bb[nt] = lnb[nt*16 + cr]; }
    #pragma unroll
    for (int r = 0; r < 4; r++){
      int y = yg*4 + r;
      #pragma unroll
      for (int reg = 0; reg < 4; reg++){
        int p = p0 + q*4 + reg;
        float v[4]; float s1 = 0.f, s2 = 0.f;
        #pragma unroll
        for (int nt = 0; nt < 4; nt++){
          v[nt] = fmaxf(acc[r][nt][reg] + bv[nt], 0.f);
          s1 += v[nt]; s2 += v[nt]*v[nt];
        }
        #pragma unroll
        for (int m = 1; m < 16; m <<= 1){ s1 += __shfl_xor(s1, m, 64); s2 += __shfl_xor(s2, m, 64); }
        float mean = s1 * (1.f/64.f);
        float var  = s2 * (1.f/64.f) - mean*mean;
        float rstd = 1.0f/sqrtf(var + 1e-5f);
        size_t base = ((size_t)b*4096 + y*64 + p)*64;
        #pragma unroll
        for (int nt = 0; nt < 4; nt++)
          out_f[base + nt*16 + cr] = (v[nt] - mean)*rstd*gv[nt] + bb[nt];
      }
    }
  }
}

// ---------------- pack 64x64 f32 [k][n] into B-fragment-ordered bf16 -------
// frag f = ks*4+nt; lane l = q*16+cr; element j: W[ks*32+q*8+j][nt*16+cr]
__global__ void k_packw1(const float* __restrict__ w1, unsigned short* __restrict__ out){
  int idx = blockIdx.x*256 + threadIdx.x;   // 4096
  int jj = idx & 7;
  int lane = (idx >> 3) & 63;
  int frag = idx >> 9;                      // 0..7
  int ks = frag >> 2, nt = frag & 3;
  int q = lane >> 4, cr = lane & 15;
  int k = ks*32 + q*8 + jj;
  int n = nt*16 + cr;
  out[idx] = bf16bits(w1[k*64 + n]);
}

// ---------------- K/V projection: enc @ toK_w, enc @ toV_w (bf16 MFMA) -----
__global__ __launch_bounds__(256) void k_projm(const float* __restrict__ enc,
                       const unsigned short* __restrict__ kpack, const float* __restrict__ bk,
                       const unsigned short* __restrict__ vpack, const float* __restrict__ bvp,
                       float* __restrict__ K, float* __restrict__ V){
  int bi = blockIdx.x; int b = bi >> 6; int tile = bi & 63;  // 1024 blocks
  int t = threadIdx.x; int wv = t >> 6; int l = t & 63;
  int q = l >> 4, cr = l & 15;
  int d0 = tile*64 + wv*16;

  const bf16x8* kp = reinterpret_cast<const bf16x8*>(kpack);
  const bf16x8* vp = reinterpret_cast<const bf16x8*>(vpack);
  bf16x8 KB[8], VB[8];
  #pragma unroll
  for (int f = 0; f < 8; f++){ KB[f] = kp[f*64 + l]; VB[f] = vp[f*64 + l]; }

  const float* er = enc + (size_t)(b*4096 + d0 + cr)*64;
  bf16x8 a0, a1;
  #pragma unroll
  for (int h = 0; h < 2; h++){
    const float4* e4 = reinterpret_cast<const float4*>(er + (h ? (32 + q*8) : (q*8)));
    #pragma unroll
    for (int p = 0; p < 2; p++){
      float4 e = e4[p];
      if (h == 0){ a0[p*4+0]=(__bf16)e.x; a0[p*4+1]=(__bf16)e.y; a0[p*4+2]=(__bf16)e.z; a0[p*4+3]=(__bf16)e.w; }
      else       { a1[p*4+0]=(__bf16)e.x; a1[p*4+1]=(__bf16)e.y; a1[p*4+2]=(__bf16)e.z; a1[p*4+3]=(__bf16)e.w; }
    }
  }

  f32x4 zero = {0.f,0.f,0.f,0.f};
  f32x4 aK[4], aV[4];
  #pragma unroll
  for (int nt = 0; nt < 4; nt++){
    aK[nt] = __builtin_amdgcn_mfma_f32_16x16x32_bf16(a0, KB[nt],     zero,   0, 0, 0);
    aK[nt] = __builtin_amdgcn_mfma_f32_16x16x32_bf16(a1, KB[4 + nt], aK[nt], 0, 0, 0);
    aV[nt] = __builtin_amdgcn_mfma_f32_16x16x32_bf16(a0, VB[nt],     zero,   0, 0, 0);
    aV[nt] = __builtin_amdgcn_mfma_f32_16x16x32_bf16(a1, VB[4 + nt], aV[nt], 0, 0, 0);
  }
  #pragma unroll
  for (int nt = 0; nt < 4; nt++){
    float bkv = bk[nt*16 + cr], bvv = bvp[nt*16 + cr];
    #pragma unroll
    for (int reg = 0; reg < 4; reg++){
      size_t base = ((size_t)b*4096 + d0 + q*4 + reg)*64 + nt*16 + cr;
      K[base] = aK[nt][reg] + bkv;
      V[base] = aV[nt][reg] + bvv;
    }
  }
}

// ---------------- per-phase prep: LN(queries), A/B/cc, w2q, zero accs ------
__global__ void k_phaseprep(const float* __restrict__ queries, const float* __restrict__ ps,
                            const float* __restrict__ qg_, const float* __restrict__ qb_,
                            const float* __restrict__ dw, const float* __restrict__ db,
                            const float* __restrict__ mlp2w, const float* __restrict__ mlp2b,
                            float* __restrict__ absc, float* __restrict__ w2qc,
                            float* __restrict__ sum_att, float* __restrict__ upd){
  int row = blockIdx.x; int e = threadIdx.x;   // 112 x 64
  float q = queries[row*64 + e];
  float m = wsum64(q) * (1.f/64.f);
  float d = q - m;
  float var = wsum64(d*d) * (1.f/64.f);
  float qlnv = d * (1.0f/sqrtf(var + 1e-5f)) * qg_[e] + qb_[e];
  float px = ps[row*3], py = ps[row*3+1], sc = ps[row*3+2];
  float A  = dw[e]      / sc;
  float Bv = dw[64 + e] / sc;
  absc[(row*3+0)*64 + e] = A;
  absc[(row*3+1)*64 + e] = Bv;
  absc[(row*3+2)*64 + e] = db[e] - px*A - py*Bv;
  // w2q[i=e] = sum_j W2[i][j] * qln[j] ; c2 = b2 . qln
  float acc = 0.f;
  const float* wrow = mlp2w + e*64;
  for (int j = 0; j < 64; j++) acc = fmaf(wrow[j], rdlane(qlnv, j), acc);
  w2qc[row*68 + e] = acc;
  float c2 = wsum64(mlp2b[e] * qlnv);
  if (e == 0) w2qc[row*68 + 64] = c2;
  upd[row*64 + e] = 0.f;
  if (e == 0) sum_att[row] = 0.f;
}

// ---------------- heavy pass: bf16 MFMA GEMM1 + fused epilogue -------------
// mode 0: outp = logits [B,S,D]; mode 1: outp = upd_pre [B,S,64] (atomic)
__global__ __launch_bounds__(256) void k_attn(const float* __restrict__ encX,
     const unsigned short* __restrict__ w1pack, const float* __restrict__ mlp1b,
     const float* __restrict__ absc, const float* __restrict__ qg_,
     const float* __restrict__ qb_, const float* __restrict__ w2qc,
     const float* __restrict__ att, const float* __restrict__ sum_att,
     float* __restrict__ outp, int mode){
  int t = threadIdx.x; int wv = t >> 6; int l = t & 63;
  int q = l >> 4, cr = l & 15;
  int bs = blockIdx.x >> 6; int tile = blockIdx.x & 63;   // 7168 blocks
  int b = bs / 7;
  int m0 = tile*64 + wv*16;           // this wave's 16-row m-tile
  int drow = m0 + cr;                 // lane's row for A-fragment build

  // B fragments of W1 (prepacked, coalesced 16B loads)
  const bf16x8* wp = reinterpret_cast<const bf16x8*>(w1pack);
  bf16x8 Bf[8];
  #pragma unroll
  for (int f = 0; f < 8; f++) Bf[f] = wp[f*64 + l];

  // build X row in A-layout: lane holds row drow, features {q*8..+7, 32+q*8..+7}
  const float* Ac = absc + bs*192;
  const float* er = encX + (size_t)(b*4096 + drow)*64;
  float gx = -0.5f + (float)(drow & 63) * (1.f/63.f);
  float gy = -0.5f + (float)((drow >> 6) & 63) * (1.f/63.f);
  float x[16];
  #pragma unroll
  for (int h = 0; h < 2; h++){
    int fb = h ? (32 + q*8) : (q*8);
    const float4* e4 = reinterpret_cast<const float4*>(er + fb);
    const float4* A4 = reinterpret_cast<const float4*>(Ac + fb);
    const float4* B4 = reinterpret_cast<const float4*>(Ac + 64 + fb);
    const float4* C4 = reinterpret_cast<const float4*>(Ac + 128 + fb);
    #pragma unroll
    for (int p = 0; p < 2; p++){
      float4 e = e4[p], Av = A4[p], Bv = B4[p], Cv = C4[p];
      int o = h*8 + p*4;
      x[o+0] = e.x + gx*Av.x + gy*Bv.x + Cv.x;
      x[o+1] = e.y + gx*Av.y + gy*Bv.y + Cv.y;
      x[o+2] = e.z + gx*Av.z + gy*Bv.z + Cv.z;
      x[o+3] = e.w + gx*Av.w + gy*Bv.w + Cv.w;
    }
  }
  // LN over the row (16 feats/lane x 4 quads): cross-quad shuffles only
  float s = 0.f;
  #pragma unroll
  for (int k = 0; k < 16; k++) s += x[k];
  s += __shfl_xor(s, 16, 64); s += __shfl_xor(s, 32, 64);
  float m = s * (1.f/64.f);
  float v = 0.f;
  #pragma unroll
  for (int k = 0; k < 16; k++){ float dd = x[k] - m; v += dd*dd; }
  v += __shfl_xor(v, 16, 64); v += __shfl_xor(v, 32, 64);
  float rstd = 1.0f/sqrtf(v * (1.f/64.f) + 1e-5f);

  bf16x8 a0, a1;
  #pragma unroll
  for (int h = 0; h < 2; h++){
    int fb = h ? (32 + q*8) : (q*8);
    const float4* g4 = reinterpret_cast<const float4*>(qg_ + fb);
    const float4* b4 = reinterpret_cast<const float4*>(qb_ + fb);
    #pragma unroll
    for (int p = 0; p < 2; p++){
      float4 gg = g4[p], bb = b4[p];
      int o = h*8 + p*4;
      float r0 = (x[o+0]-m)*rstd*gg.x + bb.x;
      float r1 = (x[o+1]-m)*rstd*gg.y + bb.y;
      float r2 = (x[o+2]-m)*rstd*gg.z + bb.z;
      float r3 = (x[o+3]-m)*rstd*gg.w + bb.w;
      if (h == 0){ a0[p*4+0]=(__bf16)r0; a0[p*4+1]=(__bf16)r1; a0[p*4+2]=(__bf16)r2; a0[p*4+3]=(__bf16)r3; }
      else       { a1[p*4+0]=(__bf16)r0; a1[p*4+1]=(__bf16)r1; a1[p*4+2]=(__bf16)r2; a1[p*4+3]=(__bf16)r3; }
    }
  }

  // GEMM1: Y[16 rows][64 cols] per wave; D: col=cr, row=q*4+reg
  f32x4 zero = {0.f, 0.f, 0.f, 0.f};
  f32x4 acc[4];
  #pragma unroll
  for (int nt = 0; nt < 4; nt++){
    acc[nt] = __builtin_amdgcn_mfma_f32_16x16x32_bf16(a0, Bf[nt],     zero,    0, 0, 0);
    acc[nt] = __builtin_amdgcn_mfma_f32_16x16x32_bf16(a1, Bf[4 + nt], acc[nt], 0, 0, 0);
  }

  if (mode == 0){
    const float* wq = w2qc + bs*68;
    float c2 = wq[64];
    float p[4] = {0.f, 0.f, 0.f, 0.f};
    #pragma unroll
    for (int nt = 0; nt < 4; nt++){
      float bb  = mlp1b[nt*16 + cr];
      float wqv = wq[nt*16 + cr];
      #pragma unroll
      for (int reg = 0; reg < 4; reg++){
        float y = fmaxf(acc[nt][reg] + bb, 0.f);
        p[reg] = fmaf(y, wqv, p[reg]);
      }
    }
    #pragma unroll
    for (int reg = 0; reg < 4; reg++){
      #pragma unroll
      for (int off = 1; off < 16; off <<= 1) p[reg] += __shfl_xor(p[reg], off, 64);
    }
    if (cr == 0){
      #pragma unroll
      for (int reg = 0; reg < 4; reg++)
        outp[bs*4096 + m0 + q*4 + reg] = (p[reg] + c2) * 0.125f;
    }
  } else {
    float sa = sum_att[bs];
    float wr[4];
    #pragma unroll
    for (int reg = 0; reg < 4; reg++)
      wr[reg] = att[bs*4096 + m0 + q*4 + reg] / sa + 1e-8f;
    float pc[4] = {0.f, 0.f, 0.f, 0.f};
    #pragma unroll
    for (int nt = 0; nt < 4; nt++){
      float bb = mlp1b[nt*16 + cr];
      #pragma unroll
      for (int reg = 0; reg < 4; reg++)
        pc[nt] = fmaf(wr[reg], fmaxf(acc[nt][reg] + bb, 0.f), pc[nt]);
    }
    #pragma unroll
    for (int nt = 0; nt < 4; nt++){
      pc[nt] += __shfl_xor(pc[nt], 16, 64);
      pc[nt] += __shfl_xor(pc[nt], 32, 64);
    }
    __shared__ float red[4][64];
    if (q == 0){
      #pragma unroll
      for (int nt = 0; nt < 4; nt++) red[wv][nt*16 + cr] = pc[nt];
    }
    __syncthreads();
    if (t < 64) atomicAdd(&outp[bs*64 + t], red[0][t] + red[1][t] + red[2][t] + red[3][t]);
  }
}

// ---------------- softmax over slots (axis=1) + per-(b,s) sums -------------
__global__ void k_softmax(float* __restrict__ att, float* __restrict__ sum_att){
  int bi = blockIdx.x;                 // 256 = B * (D/256)
  int b = bi >> 4;
  int t = threadIdx.x;
  int d = (bi & 15)*256 + t;
  int lane = t & 63; int w = t >> 6;
  __shared__ float red[4];
  float l[7];
  #pragma unroll
  for (int s = 0; s < 7; s++) l[s] = att[(b*7+s)*4096 + d];
  float m = l[0];
  #pragma unroll
  for (int s = 1; s < 7; s++) m = fmaxf(m, l[s]);
  float sum = 0.f;
  #pragma unroll
  for (int s = 0; s < 7; s++){ l[s] = expf(l[s] - m); sum += l[s]; }
  for (int s = 0; s < 7; s++){
    float a = l[s] / sum;
    att[(b*7+s)*4096 + d] = a;
    float ws = wsum64(a);
    if (lane == 0) red[w] = ws;
    __syncthreads();
    if (t == 0) atomicAdd(&sum_att[b*7+s], red[0]+red[1]+red[2]+red[3]);
    __syncthreads();
  }
}

// ---------------- update_frames + sumw -------------------------------------
__global__ void k_frames(const float* __restrict__ att, const float* __restrict__ sum_att,
                         float* __restrict__ psout, float* __restrict__ sumw){
  int bs = blockIdx.x; int t = threadIdx.x;   // 112 x 256
  float sa = sum_att[bs];
  float a0 = 0.f, ax = 0.f, ay = 0.f, a2 = 0.f;
  for (int d = t; d < 4096; d += 256){
    float wv = att[bs*4096 + d] / sa + 1e-8f;
    float gx = -0.5f + (float)(d & 63) * (1.f/63.f);
    float gy = -0.5f + (float)(d >> 6) * (1.f/63.f);
    a0 += wv; ax += wv*gx; ay += wv*gy; a2 += wv*(gx*gx + gy*gy);
  }
  __shared__ float red[4][4];
  int lane = t & 63, w = t >> 6;
  a0 = wsum64(a0); ax = wsum64(ax); ay = wsum64(ay); a2 = wsum64(a2);
  if (lane == 0){ red[w][0]=a0; red[w][1]=ax; red[w][2]=ay; red[w][3]=a2; }
  __syncthreads();
  if (t == 0){
    float W0=0,Wx=0,Wy=0,Wg=0;
    for (int k = 0; k < 4; k++){ W0+=red[k][0]; Wx+=red[k][1]; Wy+=red[k][2]; Wg+=red[k][3]; }
    // sum wts*d2 = Wg - (Wx^2+Wy^2)*(2 - W0)   (exact, since new_pos=(Wx,Wy))
    float s2 = Wg - (Wx*Wx + Wy*Wy)*(2.f - W0);
    psout[bs*3+0] = Wx; psout[bs*3+1] = Wy; psout[bs*3+2] = sqrtf(fmaxf(s2, 0.f));
    sumw[bs] = W0;
  }
}

// ---------------- GRU cell (applies folded W2 to upd_pre first) ------------
__global__ void k_gru(const float* __restrict__ upd, float* __restrict__ queries,
                      const float* __restrict__ wih, const float* __restrict__ whh,
                      const float* __restrict__ bih, const float* __restrict__ bhh,
                      const float* __restrict__ mlp2w, const float* __restrict__ mlp2b,
                      const float* __restrict__ sumw){
  int row = blockIdx.x; int t = threadIdx.x;   // 112 x 192
  __shared__ float us[64], hs[64], xs[64], gis[192], ghs[192];
  if (t < 64){ us[t] = upd[row*64 + t]; hs[t] = queries[row*64 + t]; }
  __syncthreads();
  if (t < 64){
    float a = sumw[row] * mlp2b[t];
    for (int i = 0; i < 64; i++) a = fmaf(us[i], mlp2w[i*64 + t], a);
    xs[t] = a;
  }
  __syncthreads();
  float gi = bih[t], gh = bhh[t];
  for (int e = 0; e < 64; e++){
    gi = fmaf(wih[t*64 + e], xs[e], gi);
    gh = fmaf(whh[t*64 + e], hs[e], gh);
  }
  gis[t] = gi; ghs[t] = gh;
  __syncthreads();
  if (t < 64){
    float r = 1.0f/(1.0f + expf(-(gis[t]      + ghs[t])));
    float z = 1.0f/(1.0f + expf(-(gis[64+t]   + ghs[64+t])));
    float n = tanhf(gis[128+t] + r*ghs[128+t]);
    queries[row*64 + t] = (1.0f - z)*n + z*hs[t];
  }
}

// ---------------- heads: alpha, slot_feat, copy queries --------------------
__global__ void k_final(const float* __restrict__ queries, const float* __restrict__ nps,
                        const float* __restrict__ a1w, const float* __restrict__ a1b,
                        const float* __restrict__ a2w, const float* __restrict__ a2b,
                        const float* __restrict__ f1w, const float* __restrict__ f1b,
                        const float* __restrict__ f2w, const float* __restrict__ f2b,
                        float* __restrict__ out){
  int bs = blockIdx.x; int e = threadIdx.x;    // 112 x 64
  __shared__ float qs[64], hf[64], ha[32];
  float q = queries[bs*64 + e];
  qs[e] = q;
  out[bs*64 + e] = q;                           // queries output at offset 0
  __syncthreads();
  float accf = f1b[e];
  for (int i = 0; i < 64; i++) accf = fmaf(qs[i], f1w[i*64 + e], accf);
  hf[e] = fmaxf(accf, 0.f);
  if (e < 32){
    float acca = a1b[e];
    for (int i = 0; i < 64; i++) acca = fmaf(qs[i], a1w[i*32 + e], acca);
    ha[e] = fmaxf(acca, 0.f);
  }
  __syncthreads();
  if (e < 3){
    float sf = f2b[e];
    for (int o = 0; o < 64; o++) sf = fmaf(hf[o], f2w[o*3 + e], sf);
    out[465920 + bs*3 + e] = sf + nps[bs*3 + e];   // slot_feat
  }
  if (e == 32){
    float al = a2b[0];
    for (int o = 0; o < 32; o++) al = fmaf(ha[o], a2w[o], al);
    out[466256 + bs] = 1.0f/(1.0f + expf(-al));    // alpha
  }
}

// ---------------------------------------------------------------------------
extern "C" void kernel_launch(void* const* d_in, const int* in_sizes, int n_in,
                              void* d_out, int out_size, void* d_ws, size_t ws_size,
                              hipStream_t stream){
  const float* data        = (const float*)d_in[0];
  const float* slot_noise  = (const float*)d_in[1];
  const float* pos_rand    = (const float*)d_in[2];
  const float* conv0_w     = (const float*)d_in[3];
  const float* conv0_b     = (const float*)d_in[4];
  const float* conv1_w     = (const float*)d_in[5];
  const float* conv1_b     = (const float*)d_in[6];
  const float* conv2_w     = (const float*)d_in[7];
  const float* conv2_b     = (const float*)d_in[8];
  const float* dataN_g     = (const float*)d_in[9];
  const float* dataN_b     = (const float*)d_in[10];
  const float* queryN_g    = (const float*)d_in[11];
  const float* queryN_b    = (const float*)d_in[12];
  const float* toK_w       = (const float*)d_in[13];
  const float* toK_b       = (const float*)d_in[14];
  const float* toV_w       = (const float*)d_in[15];
  const float* toV_b       = (const float*)d_in[16];
  const float* dense_w     = (const float*)d_in[17];
  const float* dense_b     = (const float*)d_in[18];
  const float* mlp1_w      = (const float*)d_in[19];
  const float* mlp1_b      = (const float*)d_in[20];
  const float* mlp2_w      = (const float*)d_in[21];
  const float* mlp2_b      = (const float*)d_in[22];
  const float* gru_wih     = (const float*)d_in[23];
  const float* gru_whh     = (const float*)d_in[24];
  const float* gru_bih     = (const float*)d_in[25];
  const float* gru_bhh     = (const float*)d_in[26];
  const float* alpha1_w    = (const float*)d_in[27];
  const float* alpha1_b    = (const float*)d_in[28];
  const float* alpha2_w    = (const float*)d_in[29];
  const float* alpha2_b    = (const float*)d_in[30];
  const float* final1_w    = (const float*)d_in[31];
  const float* final1_b    = (const float*)d_in[32];
  const float* final2_w    = (const float*)d_in[33];
  const float* final2_b    = (const float*)d_in[34];
  const float* slots_mu    = (const float*)d_in[35];
  const float* slots_lsig  = (const float*)d_in[36];

  float* ws   = (float*)d_ws;
  float* bufA = ws;                    // 4,194,304 f32 : c0_bf (as bf16) then encK
  float* bufB = bufA + 4194304;        // 4,194,304 f32 : enc
  float* bufC = bufB + 4194304;        // 4,194,304 f32 : c1_bf (as bf16) then encV
  float* attw = bufC + 4194304;        // 458,752 (logits/att, iters 0-2)
  float* queries = attw + 458752;      // 7,168
  float* ps   = queries + 7168;        // 512 (pos_scale, 336 used)
  float* absc = ps + 512;              // 21,504 (A/B/cc per (b,s))
  float* sum_att = absc + 21504;       // 128
  float* upd  = sum_att + 128;         // 7,168 (upd_pre)
  float* nps  = upd + 7168;            // 512
  float* w2qc = nps + 512;             // 7,616 (112 x 68: w2q[64] + c2)
  float* sumw = w2qc + 7616;           // 128
  unsigned short* w1pack = (unsigned short*)(sumw + 128);    // 4096 bf16 (2048 f32)
  unsigned short* kpack  = w1pack + 4096;                    // 4096 bf16
  unsigned short* vpack  = kpack + 4096;                     // 4096 bf16
  unsigned short* wp1    = vpack + 4096;                     // 102,400 bf16
  unsigned short* wp2    = wp1 + 102400;                     // 102,400 bf16
  // total ~13.2M f32 ~= 52.9 MB

  unsigned short* c0_bf = (unsigned short*)bufA;   // conv0 out, NHWC bf16
  unsigned short* c1_bf = (unsigned short*)bufC;   // conv1 out, NHWC bf16
  float* enc  = bufB;
  float* encK = bufA;
  float* encV = bufC;

  float* outq   = (float*)d_out;       // queries [112*64]
  float* outatt = outq + 7168;         // att [16*7*4096]

  k_prep<<<112, 64, 0, stream>>>(slot_noise, pos_rand, slots_mu, slots_lsig, queries, ps);
  k_packw1<<<16, 256, 0, stream>>>(mlp1_w, w1pack);
  k_packw1<<<16, 256, 0, stream>>>(toK_w, kpack);
  k_packw1<<<16, 256, 0, stream>>>(toV_w, vpack);
  k_packconv<<<400, 256, 0, stream>>>(conv1_w, wp1);
  k_packconv<<<400, 256, 0, stream>>>(conv2_w, wp2);
  k_conv0<<<1024, 256, 0, stream>>>(data, conv0_w, conv0_b, c0_bf);
  k_convm<<<256, 256, 0, stream>>>(c0_bf, wp1, conv1_b, nullptr, nullptr, c1_bf, nullptr, 0);
  k_convm<<<256, 256, 0, stream>>>(c1_bf, wp2, conv2_b, dataN_g, dataN_b, nullptr, enc, 1);
  k_projm<<<1024, 256, 0, stream>>>(enc, kpack, toK_b, vpack, toV_b, encK, encV);

  for (int p = 0; p < 4; p++){
    float* attp = (p == 3) ? outatt : attw;
    k_phaseprep<<<112, 64, 0, stream>>>(queries, ps, queryN_g, queryN_b, dense_w, dense_b,
                                        mlp2_w, mlp2_b, absc, w2qc, sum_att, upd);
    k_attn<<<7168, 256, 0, stream>>>(encK, w1pack, mlp1_b, absc, queryN_g, queryN_b,
                                     w2qc, attp, sum_att, attp, 0);
    k_softmax<<<256, 256, 0, stream>>>(attp, sum_att);
    k_frames<<<112, 256, 0, stream>>>(attp, sum_att, (p == 3) ? nps : ps, sumw);
    if (p < 3){
      k_attn<<<7168, 256, 0, stream>>>(encV, w1pack, mlp1_b, absc, queryN_g, queryN_b,
                                       w2qc, attp, sum_att, upd, 1);
      k_gru<<<112, 192, 0, stream>>>(upd, queries, gru_wih, gru_whh, gru_bih, gru_bhh,
                                     mlp2_w, mlp2_b, sumw);
    }
  }
  k_final<<<112, 64, 0, stream>>>(queries, nps, alpha1_w, alpha1_b, alpha2_w, alpha2_b,
                                  final1_w, final1_b, final2_w, final2_b, outq);
}

// Round 5
// 565.697 us; speedup vs baseline: 4.9339x; 1.0531x over previous
//
#include <hip/hip_runtime.h>
#include <cmath>

// ---------------------------------------------------------------------------
// InvariantSlotAttention forward. R5 = R4 structure with the pos_scale init
// bug fixed (reference indexes the SLOT dim: slots 0,1 get -0.5 on ALL 3
// components; slot 6 gets the r-transform on ALL 3 components).
// B=16, S=7, E=HID=64, D=4096, N_ITER=3, TSOFT=0.125
// ---------------------------------------------------------------------------

#define RLOW_F 0.1f
#define RHIGH_F 0.22360679774997896f

typedef __attribute__((ext_vector_type(8))) __bf16 bf16x8;
typedef __attribute__((ext_vector_type(4))) float f32x4;

__device__ __forceinline__ float wsum64(float v){
  #pragma unroll
  for (int off = 32; off > 0; off >>= 1) v += __shfl_xor(v, off, 64);
  return v;
}
__device__ __forceinline__ float rdlane(float v, int l){
  return __int_as_float(__builtin_amdgcn_readlane(__float_as_int(v), l));
}
__device__ __forceinline__ unsigned short bf16bits(float v){
  __bf16 h = (__bf16)v;
  return *reinterpret_cast<unsigned short*>(&h);
}

// ---- phase prep core: executed by one full wave (lanes 0..63), e = lane ---
__device__ __forceinline__ void pp_core(int row, int e, float qv,
    float px, float py, float sc,
    const float* __restrict__ qg_, const float* __restrict__ qb_,
    const float* __restrict__ dw, const float* __restrict__ db,
    const float* __restrict__ mlp2w, const float* __restrict__ mlp2b,
    float* __restrict__ absc, float* __restrict__ w2qc,
    float* __restrict__ sum_att){
  float m = wsum64(qv) * (1.f/64.f);
  float d = qv - m;
  float var = wsum64(d*d) * (1.f/64.f);
  float qlnv = d * (1.0f/sqrtf(var + 1e-5f)) * qg_[e] + qb_[e];
  float A  = dw[e]      / sc;
  float Bv = dw[64 + e] / sc;
  absc[row*192 + e]       = A;
  absc[row*192 + 64 + e]  = Bv;
  absc[row*192 + 128 + e] = db[e] - px*A - py*Bv;
  float acc = 0.f;
  const float* wrow = mlp2w + e*64;
  for (int j = 0; j < 64; j++) acc = fmaf(wrow[j], rdlane(qlnv, j), acc);
  w2qc[row*68 + e] = acc;
  float c2 = wsum64(mlp2b[e] * qlnv);
  if (e == 0){ w2qc[row*68 + 64] = c2; sum_att[row] = 0.f; }
}

// ---------------- init: queries, pos_scale, + phase-0 prep -----------------
__global__ void k_prep(const float* __restrict__ noise, const float* __restrict__ prand,
                       const float* __restrict__ mu, const float* __restrict__ logsig,
                       const float* __restrict__ qg_, const float* __restrict__ qb_,
                       const float* __restrict__ dw, const float* __restrict__ db,
                       const float* __restrict__ mlp2w, const float* __restrict__ mlp2b,
                       float* __restrict__ queries, float* __restrict__ ps,
                       float* __restrict__ absc, float* __restrict__ w2qc,
                       float* __restrict__ sum_att, float* __restrict__ upd){
  int row = blockIdx.x;            // b*7+s, 112 blocks
  int e = threadIdx.x;             // 64
  int s = row % 7;
  float qv = mu[e] + expf(logsig[e]) * noise[row*64 + e];
  queries[row*64 + e] = qv;
  upd[row*64 + e] = 0.f;
  float pv = 0.f;
  if (e < 3){
    float pr = prand[row*3 + e];
    // faithful: source indexes the SLOT dim (and swaps rlow/rhigh);
    // each selected slot transforms ALL THREE components.
    if (s < 2)       pv = pr - 0.5f;
    else if (s == 6) pv = (RLOW_F - RHIGH_F)*pr + RHIGH_F;
    else             pv = pr;
    ps[row*3 + e] = pv;
  }
  float px = rdlane(pv, 0), py = rdlane(pv, 1), sc = rdlane(pv, 2);
  pp_core(row, e, qv, px, py, sc, qg_, qb_, dw, db, mlp2w, mlp2b,
          absc, w2qc, sum_att);
}

// ---------------- conv0: 1->64 channels, 5x5 same, relu, NHWC bf16 out -----
__global__ __launch_bounds__(256) void k_conv0(const float* __restrict__ in,
                        const float* __restrict__ w, const float* __restrict__ bias,
                        unsigned short* __restrict__ out){
  int bi = blockIdx.x; int b = bi >> 6; int y = bi & 63;   // 1024 blocks
  int t = threadIdx.x; int lane = t & 63; int xg = t >> 6;
  __shared__ float s_in[5*68];
  __shared__ float s_w[64*25];
  __shared__ float s_out[64*65];
  for (int i = t; i < 1600; i += 256) s_w[i] = w[i];
  for (int i = t; i < 340; i += 256){
    int r = i / 68, cx = i % 68;
    int yy = y + r - 2, gx = cx - 2;
    float v = 0.f;
    if (yy >= 0 && yy < 64 && gx >= 0 && gx < 64) v = in[(b*64 + yy)*64 + gx];
    s_in[r*68 + cx] = v;
  }
  __syncthreads();
  int o = lane;
  float bv = bias[o];
  float acc[16];
  #pragma unroll
  for (int k = 0; k < 16; k++) acc[k] = bv;
  #pragma unroll
  for (int ky = 0; ky < 5; ky++){
    float rv[20];
    const float4* p = reinterpret_cast<const float4*>(&s_in[ky*68 + xg*16]);
    #pragma unroll
    for (int q = 0; q < 5; q++){ float4 f = p[q]; rv[q*4]=f.x; rv[q*4+1]=f.y; rv[q*4+2]=f.z; rv[q*4+3]=f.w; }
    #pragma unroll
    for (int kx = 0; kx < 5; kx++){
      float wv = s_w[o*25 + ky*5 + kx];
      #pragma unroll
      for (int k = 0; k < 16; k++) acc[k] = fmaf(rv[k+kx], wv, acc[k]);
    }
  }
  #pragma unroll
  for (int k = 0; k < 16; k++) s_out[o*65 + xg*16 + k] = fmaxf(acc[k], 0.f);
  __syncthreads();
  for (int i = t; i < 4096; i += 256){
    int px = i >> 6, ch = i & 63;
    out[((size_t)(b*64 + y)*64 + px)*64 + ch] = bf16bits(s_out[ch*65 + px]);
  }
}

// ---------------- pack conv weights [O][C][5][5] -> per-tap B-frag bf16 ----
__global__ void k_packconv(const float* __restrict__ w, unsigned short* __restrict__ out){
  int idx = blockIdx.x*256 + threadIdx.x;   // 102400
  if (idx >= 102400) return;
  int j = idx & 7;
  int l = (idx >> 3) & 63;
  int frag = idx >> 9;                      // 0..199
  int nt = frag & 3;
  int ks = (frag >> 2) % 10;
  int dy = frag / 40;
  int q = l >> 4, cr = l & 15;
  int k = ks*32 + q*8 + j;
  int kx = k >> 6, ch = k & 63;
  int n = nt*16 + cr;
  out[idx] = bf16bits(w[((n*64 + ch)*5 + dy)*5 + kx]);
}

// ---------------- conv1/conv2 as bf16 MFMA implicit GEMM -------------------
__global__ __launch_bounds__(256) void k_convm(const unsigned short* __restrict__ in_bf,
                        const unsigned short* __restrict__ wpack,
                        const float* __restrict__ bias,
                        const float* __restrict__ lng, const float* __restrict__ lnb,
                        unsigned short* __restrict__ out_bf, float* __restrict__ out_f,
                        int mode){
  int bi = blockIdx.x;                  // 256 = 16 b * 16 ygroups
  int b = bi >> 4; int yg = bi & 15;
  int t = threadIdx.x; int wv = t >> 6; int l = t & 63;
  int q = l >> 4, cr = l & 15;
  int p0 = wv*16;

  __shared__ char lds[8*68*144];

  for (int ri = 0; ri < 8; ri++){
    int yy = yg*4 + ri - 2;
    bool rok = (yy >= 0 && yy < 64);
    const uint4* src = reinterpret_cast<const uint4*>(in_bf + (size_t)(b*64 + yy)*64*64);
    for (int i = t; i < 544; i += 256){
      int px = i >> 3, c8 = i & 7;
      uint4 v = {0u,0u,0u,0u};
      int gx = px - 2;
      if (rok && gx >= 0 && gx < 64) v = src[gx*8 + c8];
      *reinterpret_cast<uint4*>(&lds[ri*9792 + px*144 + c8*16]) = v;
    }
  }
  __syncthreads();

  f32x4 acc[4][4];
  #pragma unroll
  for (int r = 0; r < 4; r++)
    #pragma unroll
    for (int nt = 0; nt < 4; nt++) acc[r][nt] = (f32x4){0.f,0.f,0.f,0.f};

  const bf16x8* wp = reinterpret_cast<const bf16x8*>(wpack);
  for (int dy = 0; dy < 5; dy++){
    for (int ks = 0; ks < 10; ks++){
      bf16x8 Bf[4];
      int fbase = (dy*10 + ks)*4;
      #pragma unroll
      for (int nt = 0; nt < 4; nt++) Bf[nt] = wp[(fbase + nt)*64 + l];
      int aoff = (p0 + cr + (ks >> 1))*144 + (ks & 1)*64 + q*16;
      #pragma unroll
      for (int r = 0; r < 4; r++){
        bf16x8 a = *reinterpret_cast<const bf16x8*>(&lds[(r + dy)*9792 + aoff]);
        #pragma unroll
        for (int nt = 0; nt < 4; nt++)
          acc[r][nt] = __builtin_amdgcn_mfma_f32_16x16x32_bf16(a, Bf[nt], acc[r][nt], 0, 0, 0);
      }
    }
  }

  float bv[4];
  #pragma unroll
  for (int nt = 0; nt < 4; nt++) bv[nt] = bias[nt*16 + cr];

  if (mode == 0){
    #pragma unroll
    for (int r = 0; r < 4; r++){
      int y = yg*4 + r;
      #pragma unroll
      for (int reg = 0; reg < 4; reg++){
        int p = p0 + q*4 + reg;
        size_t base = ((size_t)(b*64 + y)*64 + p)*64;
        #pragma unroll
        for (int nt = 0; nt < 4; nt++)
          out_bf[base + nt*16 + cr] = bf16bits(fmaxf(acc[r][nt][reg] + bv[nt], 0.f));
      }
    }
  } else {
    float gv[4], bb[4];
    #pragma unroll
    for (int nt = 0; nt < 4; nt++){ gv[nt] = lng[nt*16 + cr]; bb[nt] = lnb[nt*16 + cr]; }
    #pragma unroll
    for (int r = 0; r < 4; r++){
      int y = yg*4 + r;
      #pragma unroll
      for (int reg = 0; reg < 4; reg++){
        int p = p0 + q*4 + reg;
        float v[4]; float s1 = 0.f, s2 = 0.f;
        #pragma unroll
        for (int nt = 0; nt < 4; nt++){
          v[nt] = fmaxf(acc[r][nt][reg] + bv[nt], 0.f);
          s1 += v[nt]; s2 += v[nt]*v[nt];
        }
        #pragma unroll
        for (int m = 1; m < 16; m <<= 1){ s1 += __shfl_xor(s1, m, 64); s2 += __shfl_xor(s2, m, 64); }
        float mean = s1 * (1.f/64.f);
        float var  = s2 * (1.f/64.f) - mean*mean;
        float rstd = 1.0f/sqrtf(var + 1e-5f);
        size_t base = ((size_t)b*4096 + y*64 + p)*64;
        #pragma unroll
        for (int nt = 0; nt < 4; nt++)
          out_f[base + nt*16 + cr] = (v[nt] - mean)*rstd*gv[nt] + bb[nt];
      }
    }
  }
}

// ---------------- pack 64x64 f32 [k][n] into B-fragment-ordered bf16 -------
__global__ void k_packw1(const float* __restrict__ w1, unsigned short* __restrict__ out){
  int idx = blockIdx.x*256 + threadIdx.x;   // 4096
  int jj = idx & 7;
  int lane = (idx >> 3) & 63;
  int frag = idx >> 9;                      // 0..7
  int ks = frag >> 2, nt = frag & 3;
  int q = lane >> 4, cr = lane & 15;
  int k = ks*32 + q*8 + jj;
  int n = nt*16 + cr;
  out[idx] = bf16bits(w1[k*64 + n]);
}

// ---------------- K/V projection: enc @ toK_w, enc @ toV_w (bf16 MFMA) -----
__global__ __launch_bounds__(256) void k_projm(const float* __restrict__ enc,
                       const unsigned short* __restrict__ kpack, const float* __restrict__ bk,
                       const unsigned short* __restrict__ vpack, const float* __restrict__ bvp,
                       float* __restrict__ K, float* __restrict__ V){
  int bi = blockIdx.x; int b = bi >> 6; int tile = bi & 63;  // 1024 blocks
  int t = threadIdx.x; int wv = t >> 6; int l = t & 63;
  int q = l >> 4, cr = l & 15;
  int d0 = tile*64 + wv*16;

  const bf16x8* kp = reinterpret_cast<const bf16x8*>(kpack);
  const bf16x8* vp = reinterpret_cast<const bf16x8*>(vpack);
  bf16x8 KB[8], VB[8];
  #pragma unroll
  for (int f = 0; f < 8; f++){ KB[f] = kp[f*64 + l]; VB[f] = vp[f*64 + l]; }

  const float* er = enc + (size_t)(b*4096 + d0 + cr)*64;
  bf16x8 a0, a1;
  #pragma unroll
  for (int h = 0; h < 2; h++){
    const float4* e4 = reinterpret_cast<const float4*>(er + (h ? (32 + q*8) : (q*8)));
    #pragma unroll
    for (int p = 0; p < 2; p++){
      float4 e = e4[p];
      if (h == 0){ a0[p*4+0]=(__bf16)e.x; a0[p*4+1]=(__bf16)e.y; a0[p*4+2]=(__bf16)e.z; a0[p*4+3]=(__bf16)e.w; }
      else       { a1[p*4+0]=(__bf16)e.x; a1[p*4+1]=(__bf16)e.y; a1[p*4+2]=(__bf16)e.z; a1[p*4+3]=(__bf16)e.w; }
    }
  }

  f32x4 zero = {0.f,0.f,0.f,0.f};
  f32x4 aK[4], aV[4];
  #pragma unroll
  for (int nt = 0; nt < 4; nt++){
    aK[nt] = __builtin_amdgcn_mfma_f32_16x16x32_bf16(a0, KB[nt],     zero,   0, 0, 0);
    aK[nt] = __builtin_amdgcn_mfma_f32_16x16x32_bf16(a1, KB[4 + nt], aK[nt], 0, 0, 0);
    aV[nt] = __builtin_amdgcn_mfma_f32_16x16x32_bf16(a0, VB[nt],     zero,   0, 0, 0);
    aV[nt] = __builtin_amdgcn_mfma_f32_16x16x32_bf16(a1, VB[4 + nt], aV[nt], 0, 0, 0);
  }
  #pragma unroll
  for (int nt = 0; nt < 4; nt++){
    float bkv = bk[nt*16 + cr], bvv = bvp[nt*16 + cr];
    #pragma unroll
    for (int reg = 0; reg < 4; reg++){
      size_t base = ((size_t)b*4096 + d0 + q*4 + reg)*64 + nt*16 + cr;
      K[base] = aK[nt][reg] + bkv;
      V[base] = aV[nt][reg] + bvv;
    }
  }
}

// ---------------- attention K-pass: slot-fused GEMM1 + in-block softmax ----
__global__ __launch_bounds__(256) void k_attnK(const float* __restrict__ encX,
     const unsigned short* __restrict__ w1pack, const float* __restrict__ mlp1b,
     const float* __restrict__ absc, const float* __restrict__ qg_,
     const float* __restrict__ qb_, const float* __restrict__ w2qc,
     float* __restrict__ att, float* __restrict__ sum_att){
  int bi = blockIdx.x;                 // 1024 = 16 b * 64 tiles
  int b = bi >> 6, tile = bi & 63;
  int t = threadIdx.x; int wv = t >> 6; int l = t & 63;
  int q = l >> 4, cr = l & 15;
  int m0 = tile*64 + wv*16;
  int drow = m0 + cr;

  __shared__ float s_log[7*64];
  __shared__ float s_absc[7*192];
  __shared__ float s_wq[7*68];
  for (int i = t; i < 1344; i += 256) s_absc[i] = absc[b*7*192 + i];
  for (int i = t; i < 476;  i += 256) s_wq[i]   = w2qc[b*7*68 + i];

  const bf16x8* wp = reinterpret_cast<const bf16x8*>(w1pack);
  bf16x8 Bf[8];
  #pragma unroll
  for (int f = 0; f < 8; f++) Bf[f] = wp[f*64 + l];

  const float* er = encX + (size_t)(b*4096 + drow)*64;
  float gx = -0.5f + (float)(drow & 63) * (1.f/63.f);
  float gy = -0.5f + (float)((drow >> 6) & 63) * (1.f/63.f);
  float xb[16], gq[16], bq[16];
  #pragma unroll
  for (int h = 0; h < 2; h++){
    int fb = h ? (32 + q*8) : (q*8);
    const float4* e4 = reinterpret_cast<const float4*>(er + fb);
    const float4* g4 = reinterpret_cast<const float4*>(qg_ + fb);
    const float4* b4 = reinterpret_cast<const float4*>(qb_ + fb);
    #pragma unroll
    for (int p = 0; p < 2; p++){
      float4 e = e4[p], gg = g4[p], bb = b4[p];
      int o = h*8 + p*4;
      xb[o+0]=e.x; xb[o+1]=e.y; xb[o+2]=e.z; xb[o+3]=e.w;
      gq[o+0]=gg.x; gq[o+1]=gg.y; gq[o+2]=gg.z; gq[o+3]=gg.w;
      bq[o+0]=bb.x; bq[o+1]=bb.y; bq[o+2]=bb.z; bq[o+3]=bb.w;
    }
  }
  float b1v[4];
  #pragma unroll
  for (int nt = 0; nt < 4; nt++) b1v[nt] = mlp1b[nt*16 + cr];
  __syncthreads();

  for (int s = 0; s < 7; s++){
    const float* Ac = s_absc + s*192;
    float x[16];
    #pragma unroll
    for (int h = 0; h < 2; h++){
      int fb = h ? (32 + q*8) : (q*8);
      const float4* A4 = reinterpret_cast<const float4*>(Ac + fb);
      const float4* B4 = reinterpret_cast<const float4*>(Ac + 64 + fb);
      const float4* C4 = reinterpret_cast<const float4*>(Ac + 128 + fb);
      #pragma unroll
      for (int p = 0; p < 2; p++){
        float4 Av = A4[p], Bv = B4[p], Cv = C4[p];
        int o = h*8 + p*4;
        x[o+0] = xb[o+0] + gx*Av.x + gy*Bv.x + Cv.x;
        x[o+1] = xb[o+1] + gx*Av.y + gy*Bv.y + Cv.y;
        x[o+2] = xb[o+2] + gx*Av.z + gy*Bv.z + Cv.z;
        x[o+3] = xb[o+3] + gx*Av.w + gy*Bv.w + Cv.w;
      }
    }
    float sum = 0.f;
    #pragma unroll
    for (int k = 0; k < 16; k++) sum += x[k];
    sum += __shfl_xor(sum, 16, 64); sum += __shfl_xor(sum, 32, 64);
    float m = sum * (1.f/64.f);
    float v = 0.f;
    #pragma unroll
    for (int k = 0; k < 16; k++){ float dd = x[k] - m; v += dd*dd; }
    v += __shfl_xor(v, 16, 64); v += __shfl_xor(v, 32, 64);
    float rstd = 1.0f/sqrtf(v * (1.f/64.f) + 1e-5f);

    bf16x8 a0, a1;
    #pragma unroll
    for (int k = 0; k < 8; k++)  a0[k] = (__bf16)((x[k]   - m)*rstd*gq[k]   + bq[k]);
    #pragma unroll
    for (int k = 0; k < 8; k++)  a1[k] = (__bf16)((x[8+k] - m)*rstd*gq[8+k] + bq[8+k]);

    f32x4 zero = {0.f, 0.f, 0.f, 0.f};
    f32x4 acc[4];
    #pragma unroll
    for (int nt = 0; nt < 4; nt++){
      acc[nt] = __builtin_amdgcn_mfma_f32_16x16x32_bf16(a0, Bf[nt],     zero,    0, 0, 0);
      acc[nt] = __builtin_amdgcn_mfma_f32_16x16x32_bf16(a1, Bf[4 + nt], acc[nt], 0, 0, 0);
    }

    float c2 = s_wq[s*68 + 64];
    float p[4] = {0.f, 0.f, 0.f, 0.f};
    #pragma unroll
    for (int nt = 0; nt < 4; nt++){
      float wqv = s_wq[s*68 + nt*16 + cr];
      #pragma unroll
      for (int reg = 0; reg < 4; reg++){
        float y = fmaxf(acc[nt][reg] + b1v[nt], 0.f);
        p[reg] = fmaf(y, wqv, p[reg]);
      }
    }
    #pragma unroll
    for (int reg = 0; reg < 4; reg++){
      #pragma unroll
      for (int off = 1; off < 16; off <<= 1) p[reg] += __shfl_xor(p[reg], off, 64);
    }
    if (cr == 0){
      #pragma unroll
      for (int reg = 0; reg < 4; reg++)
        s_log[s*64 + wv*16 + q*4 + reg] = (p[reg] + c2) * 0.125f;
    }
  }
  __syncthreads();

  if (t < 64){
    float lv[7];
    #pragma unroll
    for (int s = 0; s < 7; s++) lv[s] = s_log[s*64 + t];
    float mx = lv[0];
    #pragma unroll
    for (int s = 1; s < 7; s++) mx = fmaxf(mx, lv[s]);
    float sm = 0.f;
    #pragma unroll
    for (int s = 0; s < 7; s++){ lv[s] = expf(lv[s] - mx); sm += lv[s]; }
    float inv = 1.0f / sm;
    for (int s = 0; s < 7; s++){
      float a = lv[s] * inv;
      att[(size_t)(b*7+s)*4096 + tile*64 + t] = a;
      float ws = wsum64(a);
      if (t == 0) atomicAdd(&sum_att[b*7+s], ws);
    }
  }
}

// ---------------- attention V-pass: slot-fused GEMM1 + weighted reduce -----
__global__ __launch_bounds__(256) void k_attnV(const float* __restrict__ encX,
     const unsigned short* __restrict__ w1pack, const float* __restrict__ mlp1b,
     const float* __restrict__ absc, const float* __restrict__ qg_,
     const float* __restrict__ qb_, const float* __restrict__ att,
     const float* __restrict__ sum_att, float* __restrict__ upd){
  int bi = blockIdx.x;                 // 1024
  int b = bi >> 6, tile = bi & 63;
  int t = threadIdx.x; int wv = t >> 6; int l = t & 63;
  int q = l >> 4, cr = l & 15;
  int m0 = tile*64 + wv*16;
  int drow = m0 + cr;

  __shared__ float s_absc[7*192];
  __shared__ float s_att[7*64];
  __shared__ float s_upd[7*64];
  __shared__ float s_inv[7];
  for (int i = t; i < 1344; i += 256) s_absc[i] = absc[b*7*192 + i];
  for (int i = t; i < 448;  i += 256){
    s_att[i] = att[(size_t)(b*7 + (i >> 6))*4096 + tile*64 + (i & 63)];
    s_upd[i] = 0.f;
  }
  if (t < 7) s_inv[t] = 1.0f / sum_att[b*7 + t];

  const bf16x8* wp = reinterpret_cast<const bf16x8*>(w1pack);
  bf16x8 Bf[8];
  #pragma unroll
  for (int f = 0; f < 8; f++) Bf[f] = wp[f*64 + l];

  const float* er = encX + (size_t)(b*4096 + drow)*64;
  float gx = -0.5f + (float)(drow & 63) * (1.f/63.f);
  float gy = -0.5f + (float)((drow >> 6) & 63) * (1.f/63.f);
  float xb[16], gq[16], bq[16];
  #pragma unroll
  for (int h = 0; h < 2; h++){
    int fb = h ? (32 + q*8) : (q*8);
    const float4* e4 = reinterpret_cast<const float4*>(er + fb);
    const float4* g4 = reinterpret_cast<const float4*>(qg_ + fb);
    const float4* b4 = reinterpret_cast<const float4*>(qb_ + fb);
    #pragma unroll
    for (int p = 0; p < 2; p++){
      float4 e = e4[p], gg = g4[p], bb = b4[p];
      int o = h*8 + p*4;
      xb[o+0]=e.x; xb[o+1]=e.y; xb[o+2]=e.z; xb[o+3]=e.w;
      gq[o+0]=gg.x; gq[o+1]=gg.y; gq[o+2]=gg.z; gq[o+3]=gg.w;
      bq[o+0]=bb.x; bq[o+1]=bb.y; bq[o+2]=bb.z; bq[o+3]=bb.w;
    }
  }
  float b1v[4];
  #pragma unroll
  for (int nt = 0; nt < 4; nt++) b1v[nt] = mlp1b[nt*16 + cr];
  __syncthreads();

  for (int s = 0; s < 7; s++){
    const float* Ac = s_absc + s*192;
    float x[16];
    #pragma unroll
    for (int h = 0; h < 2; h++){
      int fb = h ? (32 + q*8) : (q*8);
      const float4* A4 = reinterpret_cast<const float4*>(Ac + fb);
      const float4* B4 = reinterpret_cast<const float4*>(Ac + 64 + fb);
      const float4* C4 = reinterpret_cast<const float4*>(Ac + 128 + fb);
      #pragma unroll
      for (int p = 0; p < 2; p++){
        float4 Av = A4[p], Bv = B4[p], Cv = C4[p];
        int o = h*8 + p*4;
        x[o+0] = xb[o+0] + gx*Av.x + gy*Bv.x + Cv.x;
        x[o+1] = xb[o+1] + gx*Av.y + gy*Bv.y + Cv.y;
        x[o+2] = xb[o+2] + gx*Av.z + gy*Bv.z + Cv.z;
        x[o+3] = xb[o+3] + gx*Av.w + gy*Bv.w + Cv.w;
      }
    }
    float sum = 0.f;
    #pragma unroll
    for (int k = 0; k < 16; k++) sum += x[k];
    sum += __shfl_xor(sum, 16, 64); sum += __shfl_xor(sum, 32, 64);
    float m = sum * (1.f/64.f);
    float v = 0.f;
    #pragma unroll
    for (int k = 0; k < 16; k++){ float dd = x[k] - m; v += dd*dd; }
    v += __shfl_xor(v, 16, 64); v += __shfl_xor(v, 32, 64);
    float rstd = 1.0f/sqrtf(v * (1.f/64.f) + 1e-5f);

    bf16x8 a0, a1;
    #pragma unroll
    for (int k = 0; k < 8; k++)  a0[k] = (__bf16)((x[k]   - m)*rstd*gq[k]   + bq[k]);
    #pragma unroll
    for (int k = 0; k < 8; k++)  a1[k] = (__bf16)((x[8+k] - m)*rstd*gq[8+k] + bq[8+k]);

    f32x4 zero = {0.f, 0.f, 0.f, 0.f};
    f32x4 acc[4];
    #pragma unroll
    for (int nt = 0; nt < 4; nt++){
      acc[nt] = __builtin_amdgcn_mfma_f32_16x16x32_bf16(a0, Bf[nt],     zero,    0, 0, 0);
      acc[nt] = __builtin_amdgcn_mfma_f32_16x16x32_bf16(a1, Bf[4 + nt], acc[nt], 0, 0, 0);
    }

    float rsa = s_inv[s];
    float wr[4];
    #pragma unroll
    for (int reg = 0; reg < 4; reg++)
      wr[reg] = fmaf(s_att[s*64 + wv*16 + q*4 + reg], rsa, 1e-8f);
    float pc[4];
    #pragma unroll
    for (int nt = 0; nt < 4; nt++){
      pc[nt] = 0.f;
      #pragma unroll
      for (int reg = 0; reg < 4; reg++)
        pc[nt] = fmaf(wr[reg], fmaxf(acc[nt][reg] + b1v[nt], 0.f), pc[nt]);
    }
    #pragma unroll
    for (int nt = 0; nt < 4; nt++){
      pc[nt] += __shfl_xor(pc[nt], 16, 64);
      pc[nt] += __shfl_xor(pc[nt], 32, 64);
    }
    if (q == 0){
      #pragma unroll
      for (int nt = 0; nt < 4; nt++)
        atomicAdd(&s_upd[s*64 + nt*16 + cr], pc[nt]);
    }
  }
  __syncthreads();
  for (int i = t; i < 448; i += 256)
    atomicAdd(&upd[b*448 + i], s_upd[i]);
}

// ---------------- update_frames + sumw -------------------------------------
__global__ void k_frames(const float* __restrict__ att, const float* __restrict__ sum_att,
                         float* __restrict__ psout, float* __restrict__ sumw){
  int bs = blockIdx.x; int t = threadIdx.x;   // 112 x 256
  float sa = sum_att[bs];
  float a0 = 0.f, ax = 0.f, ay = 0.f, a2 = 0.f;
  for (int d = t; d < 4096; d += 256){
    float wv = att[bs*4096 + d] / sa + 1e-8f;
    float gx = -0.5f + (float)(d & 63) * (1.f/63.f);
    float gy = -0.5f + (float)(d >> 6) * (1.f/63.f);
    a0 += wv; ax += wv*gx; ay += wv*gy; a2 += wv*(gx*gx + gy*gy);
  }
  __shared__ float red[4][4];
  int lane = t & 63, w = t >> 6;
  a0 = wsum64(a0); ax = wsum64(ax); ay = wsum64(ay); a2 = wsum64(a2);
  if (lane == 0){ red[w][0]=a0; red[w][1]=ax; red[w][2]=ay; red[w][3]=a2; }
  __syncthreads();
  if (t == 0){
    float W0=0,Wx=0,Wy=0,Wg=0;
    for (int k = 0; k < 4; k++){ W0+=red[k][0]; Wx+=red[k][1]; Wy+=red[k][2]; Wg+=red[k][3]; }
    float s2 = Wg - (Wx*Wx + Wy*Wy)*(2.f - W0);
    psout[bs*3+0] = Wx; psout[bs*3+1] = Wy; psout[bs*3+2] = sqrtf(fmaxf(s2, 0.f));
    sumw[bs] = W0;
  }
}

// ---------------- GRU cell + next-phase prep --------------------------------
__global__ void k_gru(float* __restrict__ upd, float* __restrict__ queries,
                      const float* __restrict__ wih, const float* __restrict__ whh,
                      const float* __restrict__ bih, const float* __restrict__ bhh,
                      const float* __restrict__ mlp2w, const float* __restrict__ mlp2b,
                      const float* __restrict__ sumw, const float* __restrict__ ps,
                      const float* __restrict__ qg_, const float* __restrict__ qb_,
                      const float* __restrict__ dw, const float* __restrict__ db,
                      float* __restrict__ absc, float* __restrict__ w2qc,
                      float* __restrict__ sum_att){
  int row = blockIdx.x; int t = threadIdx.x;   // 112 x 192
  __shared__ float us[64], hs[64], xs[64], gis[192], ghs[192];
  if (t < 64){ us[t] = upd[row*64 + t]; hs[t] = queries[row*64 + t]; }
  __syncthreads();
  if (t < 64){
    float a = sumw[row] * mlp2b[t];
    for (int i = 0; i < 64; i++) a = fmaf(us[i], mlp2w[i*64 + t], a);
    xs[t] = a;
  }
  __syncthreads();
  float gi = bih[t], gh = bhh[t];
  for (int e = 0; e < 64; e++){
    gi = fmaf(wih[t*64 + e], xs[e], gi);
    gh = fmaf(whh[t*64 + e], hs[e], gh);
  }
  gis[t] = gi; ghs[t] = gh;
  __syncthreads();
  if (t < 64){
    float r = 1.0f/(1.0f + expf(-(gis[t]      + ghs[t])));
    float z = 1.0f/(1.0f + expf(-(gis[64+t]   + ghs[64+t])));
    float n = tanhf(gis[128+t] + r*ghs[128+t]);
    float newq = (1.0f - z)*n + z*hs[t];
    queries[row*64 + t] = newq;
    upd[row*64 + t] = 0.f;
    float px = ps[row*3], py = ps[row*3+1], sc = ps[row*3+2];
    pp_core(row, t, newq, px, py, sc, qg_, qb_, dw, db, mlp2w, mlp2b,
            absc, w2qc, sum_att);
  }
}

// ---------------- heads: alpha, slot_feat, copy queries --------------------
__global__ void k_final(const float* __restrict__ queries, const float* __restrict__ nps,
                        const float* __restrict__ a1w, const float* __restrict__ a1b,
                        const float* __restrict__ a2w, const float* __restrict__ a2b,
                        const float* __restrict__ f1w, const float* __restrict__ f1b,
                        const float* __restrict__ f2w, const float* __restrict__ f2b,
                        float* __restrict__ out){
  int bs = blockIdx.x; int e = threadIdx.x;    // 112 x 64
  __shared__ float qs[64], hf[64], ha[32];
  float q = queries[bs*64 + e];
  qs[e] = q;
  out[bs*64 + e] = q;                           // queries output at offset 0
  __syncthreads();
  float accf = f1b[e];
  for (int i = 0; i < 64; i++) accf = fmaf(qs[i], f1w[i*64 + e], accf);
  hf[e] = fmaxf(accf, 0.f);
  if (e < 32){
    float acca = a1b[e];
    for (int i = 0; i < 64; i++) acca = fmaf(qs[i], a1w[i*32 + e], acca);
    ha[e] = fmaxf(acca, 0.f);
  }
  __syncthreads();
  if (e < 3){
    float sf = f2b[e];
    for (int o = 0; o < 64; o++) sf = fmaf(hf[o], f2w[o*3 + e], sf);
    out[465920 + bs*3 + e] = sf + nps[bs*3 + e];   // slot_feat
  }
  if (e == 32){
    float al = a2b[0];
    for (int o = 0; o < 32; o++) al = fmaf(ha[o], a2w[o], al);
    out[466256 + bs] = 1.0f/(1.0f + expf(-al));    // alpha
  }
}

// ---------------------------------------------------------------------------
extern "C" void kernel_launch(void* const* d_in, const int* in_sizes, int n_in,
                              void* d_out, int out_size, void* d_ws, size_t ws_size,
                              hipStream_t stream){
  const float* data        = (const float*)d_in[0];
  const float* slot_noise  = (const float*)d_in[1];
  const float* pos_rand    = (const float*)d_in[2];
  const float* conv0_w     = (const float*)d_in[3];
  const float* conv0_b     = (const float*)d_in[4];
  const float* conv1_w     = (const float*)d_in[5];
  const float* conv1_b     = (const float*)d_in[6];
  const float* conv2_w     = (const float*)d_in[7];
  const float* conv2_b     = (const float*)d_in[8];
  const float* dataN_g     = (const float*)d_in[9];
  const float* dataN_b     = (const float*)d_in[10];
  const float* queryN_g    = (const float*)d_in[11];
  const float* queryN_b    = (const float*)d_in[12];
  const float* toK_w       = (const float*)d_in[13];
  const float* toK_b       = (const float*)d_in[14];
  const float* toV_w       = (const float*)d_in[15];
  const float* toV_b       = (const float*)d_in[16];
  const float* dense_w     = (const float*)d_in[17];
  const float* dense_b     = (const float*)d_in[18];
  const float* mlp1_w      = (const float*)d_in[19];
  const float* mlp1_b      = (const float*)d_in[20];
  const float* mlp2_w      = (const float*)d_in[21];
  const float* mlp2_b      = (const float*)d_in[22];
  const float* gru_wih     = (const float*)d_in[23];
  const float* gru_whh     = (const float*)d_in[24];
  const float* gru_bih     = (const float*)d_in[25];
  const float* gru_bhh     = (const float*)d_in[26];
  const float* alpha1_w    = (const float*)d_in[27];
  const float* alpha1_b    = (const float*)d_in[28];
  const float* alpha2_w    = (const float*)d_in[29];
  const float* alpha2_b    = (const float*)d_in[30];
  const float* final1_w    = (const float*)d_in[31];
  const float* final1_b    = (const float*)d_in[32];
  const float* final2_w    = (const float*)d_in[33];
  const float* final2_b    = (const float*)d_in[34];
  const float* slots_mu    = (const float*)d_in[35];
  const float* slots_lsig  = (const float*)d_in[36];

  float* ws   = (float*)d_ws;
  float* bufA = ws;                    // 4,194,304 f32 : c0_bf (bf16) then encK
  float* bufB = bufA + 4194304;        // 4,194,304 f32 : enc
  float* bufC = bufB + 4194304;        // 4,194,304 f32 : c1_bf (bf16) then encV
  float* attw = bufC + 4194304;        // 458,752 (att, iters 0-2)
  float* queries = attw + 458752;      // 7,168
  float* ps   = queries + 7168;        // 512 (pos_scale, 336 used)
  float* absc = ps + 512;              // 21,504 (A/B/cc per (b,s))
  float* sum_att = absc + 21504;       // 128
  float* upd  = sum_att + 128;         // 7,168 (upd_pre)
  float* nps  = upd + 7168;            // 512
  float* w2qc = nps + 512;             // 7,616 (112 x 68)
  float* sumw = w2qc + 7616;           // 128
  unsigned short* w1pack = (unsigned short*)(sumw + 128);    // 4096 bf16
  unsigned short* kpack  = w1pack + 4096;                    // 4096 bf16
  unsigned short* vpack  = kpack + 4096;                     // 4096 bf16
  unsigned short* wp1    = vpack + 4096;                     // 102,400 bf16
  unsigned short* wp2    = wp1 + 102400;                     // 102,400 bf16

  unsigned short* c0_bf = (unsigned short*)bufA;   // conv0 out, NHWC bf16
  unsigned short* c1_bf = (unsigned short*)bufC;   // conv1 out, NHWC bf16
  float* enc  = bufB;
  float* encK = bufA;
  float* encV = bufC;

  float* outq   = (float*)d_out;       // queries [112*64]
  float* outatt = outq + 7168;         // att [16*7*4096]

  k_prep<<<112, 64, 0, stream>>>(slot_noise, pos_rand, slots_mu, slots_lsig,
                                 queryN_g, queryN_b, dense_w, dense_b, mlp2_w, mlp2_b,
                                 queries, ps, absc, w2qc, sum_att, upd);
  k_packw1<<<16, 256, 0, stream>>>(mlp1_w, w1pack);
  k_packw1<<<16, 256, 0, stream>>>(toK_w, kpack);
  k_packw1<<<16, 256, 0, stream>>>(toV_w, vpack);
  k_packconv<<<400, 256, 0, stream>>>(conv1_w, wp1);
  k_packconv<<<400, 256, 0, stream>>>(conv2_w, wp2);
  k_conv0<<<1024, 256, 0, stream>>>(data, conv0_w, conv0_b, c0_bf);
  k_convm<<<256, 256, 0, stream>>>(c0_bf, wp1, conv1_b, nullptr, nullptr, c1_bf, nullptr, 0);
  k_convm<<<256, 256, 0, stream>>>(c1_bf, wp2, conv2_b, dataN_g, dataN_b, nullptr, enc, 1);
  k_projm<<<1024, 256, 0, stream>>>(enc, kpack, toK_b, vpack, toV_b, encK, encV);

  for (int p = 0; p < 4; p++){
    float* attp = (p == 3) ? outatt : attw;
    k_attnK<<<1024, 256, 0, stream>>>(encK, w1pack, mlp1_b, absc, queryN_g, queryN_b,
                                      w2qc, attp, sum_att);
    k_frames<<<112, 256, 0, stream>>>(attp, sum_att, (p == 3) ? nps : ps, sumw);
    if (p < 3){
      k_attnV<<<1024, 256, 0, stream>>>(encV, w1pack, mlp1_b, absc, queryN_g, queryN_b,
                                        attp, sum_att, upd);
      k_gru<<<112, 192, 0, stream>>>(upd, queries, gru_wih, gru_whh, gru_bih, gru_bhh,
                                     mlp2_w, mlp2_b, sumw, ps, queryN_g, queryN_b,
                                     dense_w, dense_b, absc, w2qc, sum_att);
    }
  }
  k_final<<<112, 64, 0, stream>>>(queries, nps, alpha1_w, alpha1_b, alpha2_w, alpha2_b,
                                  final1_w, final1_b, final2_w, final2_b, outq);
}